// Round 1
// baseline (270.328 us; speedup 1.0000x reference)
//
#include <hip/hip_runtime.h>
#include <hip/hip_bf16.h>
#include <stdint.h>

typedef __hip_bfloat16 bf16;
typedef __attribute__((ext_vector_type(8))) short short8;
typedef __attribute__((ext_vector_type(4))) float f32x4;

#define EPS_ATTN 1e-6f
#define EPS_LN   1e-5f

// ---------------------------------------------------------------------------
// async global->LDS, 16B per lane. LDS dest = wave-uniform base + lane*16.
// ---------------------------------------------------------------------------
__device__ __forceinline__ void async16(const void* g, void* l) {
    __builtin_amdgcn_global_load_lds(
        (const __attribute__((address_space(1))) void*)g,
        (__attribute__((address_space(3))) void*)l,
        16, 0, 0);
}

// ---------------------------------------------------------------------------
// fp32 -> bf16 convert
// ---------------------------------------------------------------------------
__global__ void k_cvt(const float* __restrict__ in, bf16* __restrict__ out, long n)
{
    const long id = (long)blockIdx.x * 256 + threadIdx.x;
    if (id < n) out[id] = __float2bfloat16(in[id]);
}

// ---------------------------------------------------------------------------
// W [K,N] fp32 -> WT [N,K] bf16   (writes coalesced, reads strided; tiny)
// ---------------------------------------------------------------------------
__global__ void k_transpose(const float* __restrict__ W, bf16* __restrict__ WT,
                            int K, int N)
{
    const int id = blockIdx.x * 256 + threadIdx.x;
    if (id >= K * N) return;
    const int n = id / K, k = id % K;
    WT[id] = __float2bfloat16(W[(long)k * N + n]);
}

// ---------------------------------------------------------------------------
// GEMM: C[M,N] = A[M,K] @ W[K,N], W given pre-transposed as BT[N,K] (bf16).
// m97 structure: 128x128 tile, BK=64, 4 waves (2x2 of 64x64), 16x16x32 MFMA,
// global_load_lds width=16 staging, linear LDS, 2 barriers per K-step.
// EPI: 0 = none (fp32 out), 1 = elu+1 (bf16), 2 = *escale (bf16), 3 = relu (bf16)
// ---------------------------------------------------------------------------
template<int EPI>
__global__ __launch_bounds__(256)
void k_gemm(const bf16* __restrict__ A, const bf16* __restrict__ BT,
            void* __restrict__ C, int M, int N, int K, float escale)
{
    __shared__ __attribute__((aligned(16))) bf16 Asm[128 * 64];
    __shared__ __attribute__((aligned(16))) bf16 Bsm[128 * 64];
    const int tid  = threadIdx.x;
    const int wave = tid >> 6, lane = tid & 63;
    const int wm = wave >> 1, wn = wave & 1;
    const long row0 = (long)blockIdx.x * 128;
    const long col0 = (long)blockIdx.y * 128;

    f32x4 acc[4][4] = {};

    const int lr = lane >> 3;        // row within an 8-row staging group
    const int lc = (lane & 7) * 8;   // elem offset within 64-wide k window

    for (int kt = 0; kt < K; kt += 64) {
        #pragma unroll
        for (int i = 0; i < 4; ++i) {
            const int grp = wave * 4 + i;            // 0..15
            const long r  = grp * 8 + lr;
            async16(A  + (row0 + r) * K + kt + lc, &Asm[grp * 512]);
            async16(BT + (col0 + r) * K + kt + lc, &Bsm[grp * 512]);
        }
        __syncthreads();
        #pragma unroll
        for (int ks = 0; ks < 2; ++ks) {
            short8 a[4], b[4];
            #pragma unroll
            for (int m = 0; m < 4; ++m)
                a[m] = *(const short8*)&Asm[(wm*64 + m*16 + (lane & 15))*64 + ks*32 + (lane>>4)*8];
            #pragma unroll
            for (int n = 0; n < 4; ++n)
                b[n] = *(const short8*)&Bsm[(wn*64 + n*16 + (lane & 15))*64 + ks*32 + (lane>>4)*8];
            #pragma unroll
            for (int m = 0; m < 4; ++m)
                #pragma unroll
                for (int n = 0; n < 4; ++n)
                    acc[m][n] = __builtin_amdgcn_mfma_f32_16x16x32_bf16(a[m], b[n], acc[m][n], 0, 0, 0);
        }
        __syncthreads();
    }

    // epilogue: C/D layout col=lane&15, row=(lane>>4)*4+reg  [m89]
    #pragma unroll
    for (int m = 0; m < 4; ++m) {
        #pragma unroll
        for (int n = 0; n < 4; ++n) {
            #pragma unroll
            for (int r = 0; r < 4; ++r) {
                const long row = row0 + wm*64 + m*16 + (lane >> 4)*4 + r;
                const long col = col0 + wn*64 + n*16 + (lane & 15);
                float v = acc[m][n][r];
                if constexpr (EPI == 1) v = v > 0.f ? v + 1.f : __expf(v); // elu(v)+1
                if constexpr (EPI == 2) v *= escale;
                if constexpr (EPI == 3) v = v > 0.f ? v : 0.f;
                if constexpr (EPI == 0) ((float*)C)[row * N + col] = v;
                else                    ((bf16*)C)[row * N + col] = __float2bfloat16(v);
            }
        }
    }
}

// ---------------------------------------------------------------------------
// Partial KV / Ksum. Grid (64 s-chunks, 4 batches). Thread t = (h = t>>5, d).
// partKV[c][n][h*32+d][v], partKs[c][n][t]. Deterministic (no atomics).
// ---------------------------------------------------------------------------
__global__ __launch_bounds__(256)
void k_kv(const bf16* __restrict__ Kb, const bf16* __restrict__ Vb,
          float* __restrict__ partKV, float* __restrict__ partKs)
{
    __shared__ float k16[16][256];
    __shared__ float v16[16][256];
    const int c = blockIdx.x;   // 0..63, 128 rows each
    const int n = blockIdx.y;   // 0..3
    const int t = threadIdx.x;
    const int h = t >> 5, dd = t & 31;
    float acc[32] = {};
    float ks = 0.f;
    const long base = ((long)n * 8192 + (long)c * 128) * 256;
    for (int s0 = 0; s0 < 128; s0 += 16) {
        #pragma unroll
        for (int i = 0; i < 16; ++i) {
            k16[i][t] = __bfloat162float(Kb[base + (long)(s0 + i) * 256 + t]);
            v16[i][t] = __bfloat162float(Vb[base + (long)(s0 + i) * 256 + t]);
        }
        __syncthreads();
        #pragma unroll
        for (int i = 0; i < 16; ++i) {
            const float kd = k16[i][h * 32 + dd];
            ks += kd;
            #pragma unroll
            for (int v = 0; v < 32; ++v) acc[v] += kd * v16[i][h * 32 + v];
        }
        __syncthreads();
    }
    const long pb = (long)(c * 4 + n) * 8192 + (long)t * 32;
    #pragma unroll
    for (int v = 0; v < 32; ++v) partKV[pb + v] = acc[v];
    partKs[(c * 4 + n) * 256 + t] = ks;
}

__global__ void k_kv_reduce(const float* __restrict__ partKV,
                            const float* __restrict__ partKs,
                            float* __restrict__ KV, float* __restrict__ Ksum)
{
    const int id = blockIdx.x * 256 + threadIdx.x;
    if (id >= 4 * 8448) return;
    const int n = id / 8448, j = id % 8448;
    float s = 0.f;
    if (j < 8192) {
        for (int c = 0; c < 64; ++c) s += partKV[(long)(c * 4 + n) * 8192 + j];
        KV[n * 8192 + j] = s;
    } else {
        const int jj = j - 8192;
        for (int c = 0; c < 64; ++c) s += partKs[(c * 4 + n) * 256 + jj];
        Ksum[n * 256 + jj] = s;
    }
}

// ---------------------------------------------------------------------------
// msg1[n,l,h,v] = (sum_d Q[n,l,h,d]*KV[n,h,d,v]) / (Q.Ksum + eps) * S
// Block: 32 rows; KV[n] (32 KB) staged in LDS. Thread t = (h = t>>5, v).
// ---------------------------------------------------------------------------
__global__ __launch_bounds__(256)
void k_attn(const bf16* __restrict__ Qb, const float* __restrict__ KV,
            const float* __restrict__ Ksum, bf16* __restrict__ msg1)
{
    __shared__ float kvs[8192];
    __shared__ float kss[256];
    __shared__ float qr[4][256];
    const int chunk = blockIdx.x;  // 0..255
    const int n = blockIdx.y;
    const int t = threadIdx.x;
    const int h = t >> 5, v = t & 31;
    for (int i = t; i < 8192; i += 256) kvs[i] = KV[n * 8192 + i];
    kss[t] = Ksum[n * 256 + t];
    __syncthreads();
    const long rowbase = (long)n * 8192 + (long)chunk * 32;
    for (int r0 = 0; r0 < 32; r0 += 4) {
        #pragma unroll
        for (int i = 0; i < 4; ++i)
            qr[i][t] = __bfloat162float(Qb[(rowbase + r0 + i) * 256 + t]);
        __syncthreads();
        #pragma unroll
        for (int i = 0; i < 4; ++i) {
            float z = 0.f, acc = 0.f;
            const float* kvh = &kvs[h * 1024];
            #pragma unroll
            for (int d = 0; d < 32; ++d) {
                const float q = qr[i][h * 32 + d];
                z   += q * kss[h * 32 + d];
                acc += q * kvh[d * 32 + v];
            }
            const float outv = acc * (1.f / (z + EPS_ATTN)) * 8192.f;
            msg1[(rowbase + r0 + i) * 256 + t] = __float2bfloat16(outv);
        }
        __syncthreads();
    }
}

// ---------------------------------------------------------------------------
// LayerNorm helpers (one 256-thread block per row of 256)
// ---------------------------------------------------------------------------
__device__ __forceinline__ float block_reduce_sum(float v, float* ws)
{
    #pragma unroll
    for (int o = 32; o > 0; o >>= 1) v += __shfl_xor(v, o);
    const int wave = threadIdx.x >> 6;
    __syncthreads();
    if ((threadIdx.x & 63) == 0) ws[wave] = v;
    __syncthreads();
    return ws[0] + ws[1] + ws[2] + ws[3];
}

// LN1 + build hcat = [x_bf | LN(msgm)] (bf16 [32768,512])
__global__ __launch_bounds__(256)
void k_ln1_hcat(const float* __restrict__ msgm, const float* __restrict__ g,
                const float* __restrict__ b, const bf16* __restrict__ xb,
                bf16* __restrict__ hcat)
{
    __shared__ float ws[4];
    const long row = blockIdx.x;
    const int t = threadIdx.x;
    const float v  = msgm[row * 256 + t];
    const float mu = block_reduce_sum(v, ws) * (1.f / 256.f);
    const float dv = v - mu;
    const float var = block_reduce_sum(dv * dv, ws) * (1.f / 256.f);
    const float y = dv * rsqrtf(var + EPS_LN) * g[t] + b[t];
    hcat[row * 512 + t]       = xb[row * 256 + t];
    hcat[row * 512 + 256 + t] = __float2bfloat16(y);
}

// LN2 + residual: out = x + LN(msg2)   (fp32)
__global__ __launch_bounds__(256)
void k_ln2_res(const float* __restrict__ msg2, const float* __restrict__ g,
               const float* __restrict__ b, const float* __restrict__ x,
               float* __restrict__ out)
{
    __shared__ float ws[4];
    const long row = blockIdx.x;
    const int t = threadIdx.x;
    const float v  = msg2[row * 256 + t];
    const float mu = block_reduce_sum(v, ws) * (1.f / 256.f);
    const float dv = v - mu;
    const float var = block_reduce_sum(dv * dv, ws) * (1.f / 256.f);
    const float y = dv * rsqrtf(var + EPS_LN) * g[t] + b[t];
    out[row * 256 + t] = x[row * 256 + t] + y;
}

// ---------------------------------------------------------------------------
extern "C" void kernel_launch(void* const* d_in, const int* in_sizes, int n_in,
                              void* d_out, int out_size, void* d_ws, size_t ws_size,
                              hipStream_t stream)
{
    const float* x      = (const float*)d_in[0];
    const float* source = (const float*)d_in[1];
    const float* Wq     = (const float*)d_in[2];
    const float* Wk     = (const float*)d_in[3];
    const float* Wv     = (const float*)d_in[4];
    const float* Wm     = (const float*)d_in[5];
    const float* W1     = (const float*)d_in[6];
    const float* W2     = (const float*)d_in[7];
    const float* g1     = (const float*)d_in[8];
    const float* b1     = (const float*)d_in[9];
    const float* g2     = (const float*)d_in[10];
    const float* b2     = (const float*)d_in[11];
    float* out = (float*)d_out;

    const long M = 32768;                 // N*L = 4*8192 rows
    const size_t U = 32768ull * 256ull;   // one activation slot (elements)
    char* w = (char*)d_ws;

    // slot layout (each slot = U bf16 elements = 16 MB); lifetimes verified:
    bf16* x_bf  = (bf16*)(w + 0 * U * 2);
    bf16* s_bf  = (bf16*)(w + 1 * U * 2);
    bf16* Q_bf  = (bf16*)(w + 2 * U * 2);
    bf16* K_bf  = (bf16*)(w + 3 * U * 2);
    bf16* V_bf  = (bf16*)(w + 4 * U * 2);
    bf16* msg1  = (bf16*)(w + 5 * U * 2);
    float* msgm = (float*)(w + 3 * U * 2);  // slots 3-4 (K,V dead after k_kv)
    bf16* hcat  = (bf16*)(w + 1 * U * 2);   // slots 1-2 (src,Q dead)
    bf16* t_bf  = (bf16*)(w + 3 * U * 2);   // slots 3-4 (msgm dead after ln1)
    float* msg2 = (float*)(w + 5 * U * 2);  // slots 5-6 (msg1 dead)

    char* wx = w + 7 * U * 2;
    bf16* WqT = (bf16*)wx; wx += 65536 * 2;
    bf16* WkT = (bf16*)wx; wx += 65536 * 2;
    bf16* WvT = (bf16*)wx; wx += 65536 * 2;
    bf16* WmT = (bf16*)wx; wx += 65536 * 2;
    bf16* W1T = (bf16*)wx; wx += 262144 * 2;
    bf16* W2T = (bf16*)wx; wx += 131072 * 2;
    float* partKV = (float*)wx; wx += 2097152 * 4;
    float* partKs = (float*)wx; wx += 65536 * 4;
    float* KV     = (float*)wx; wx += 32768 * 4;
    float* Ksum   = (float*)wx; wx += 1024 * 4;

    const dim3 blk(256);

    // 1) converts + weight transposes
    k_cvt<<<32768, blk, 0, stream>>>(x, x_bf, M * 256);
    k_cvt<<<32768, blk, 0, stream>>>(source, s_bf, M * 256);
    k_transpose<<<256,  blk, 0, stream>>>(Wq, WqT, 256, 256);
    k_transpose<<<256,  blk, 0, stream>>>(Wk, WkT, 256, 256);
    k_transpose<<<256,  blk, 0, stream>>>(Wv, WvT, 256, 256);
    k_transpose<<<256,  blk, 0, stream>>>(Wm, WmT, 256, 256);
    k_transpose<<<1024, blk, 0, stream>>>(W1, W1T, 512, 512);
    k_transpose<<<512,  blk, 0, stream>>>(W2, W2T, 512, 256);

    // 2) projections: Q = fmap(x@Wq), K = fmap(src@Wk), Vn = (src@Wv)/S
    k_gemm<1><<<dim3(256, 2), blk, 0, stream>>>(x_bf, WqT, Q_bf, 32768, 256, 256, 0.f);
    k_gemm<1><<<dim3(256, 2), blk, 0, stream>>>(s_bf, WkT, K_bf, 32768, 256, 256, 0.f);
    k_gemm<2><<<dim3(256, 2), blk, 0, stream>>>(s_bf, WvT, V_bf, 32768, 256, 256, 1.f / 8192.f);

    // 3) KV = sum_s K^T Vn per head, Ksum = sum_s K (deterministic partials)
    k_kv<<<dim3(64, 4), blk, 0, stream>>>(K_bf, V_bf, partKV, partKs);
    k_kv_reduce<<<132, blk, 0, stream>>>(partKV, partKs, KV, Ksum);

    // 4) attention matvec -> msg1
    k_attn<<<dim3(256, 4), blk, 0, stream>>>(Q_bf, KV, Ksum, msg1);

    // 5) merge GEMM (fp32 out), LN1 + hcat
    k_gemm<0><<<dim3(256, 2), blk, 0, stream>>>(msg1, WmT, msgm, 32768, 256, 256, 0.f);
    k_ln1_hcat<<<32768, blk, 0, stream>>>(msgm, g1, b1, x_bf, hcat);

    // 6) MLP: t = relu(hcat@W1), msg2 = t@W2 (fp32)
    k_gemm<3><<<dim3(256, 4), blk, 0, stream>>>(hcat, W1T, t_bf, 32768, 512, 512, 0.f);
    k_gemm<0><<<dim3(256, 2), blk, 0, stream>>>(t_bf, W2T, msg2, 32768, 256, 512, 0.f);

    // 7) LN2 + residual
    k_ln2_res<<<32768, blk, 0, stream>>>(msg2, g2, b2, x, out);
}

// Round 3
// 228.540 us; speedup vs baseline: 1.1829x; 1.1829x over previous
//
#include <hip/hip_runtime.h>
#include <hip/hip_bf16.h>
#include <stdint.h>

typedef __hip_bfloat16 bf16;
typedef __attribute__((ext_vector_type(8))) short short8;
typedef __attribute__((ext_vector_type(4))) short bf16x4;
typedef __attribute__((ext_vector_type(4))) float f32x4;

#define EPS_ATTN 1e-6f
#define EPS_LN   1e-5f

__device__ __forceinline__ float b2f(short s) {
    return __builtin_bit_cast(float, (unsigned)((unsigned short)s) << 16);
}
__device__ __forceinline__ short f2b(float f) {
    return __builtin_bit_cast(short, __float2bfloat16(f));
}

// ---------------------------------------------------------------------------
// async global->LDS, 16B per lane. LDS dest = wave-uniform base + lane*16.
// ---------------------------------------------------------------------------
__device__ __forceinline__ void async16(const void* g, void* l) {
    __builtin_amdgcn_global_load_lds(
        (const __attribute__((address_space(1))) void*)g,
        (__attribute__((address_space(3))) void*)l,
        16, 0, 0);
}

// ---------------------------------------------------------------------------
// fp32 -> bf16 convert, 8 elements/thread (2x float4 in, 1x short8 out)
// ---------------------------------------------------------------------------
__global__ __launch_bounds__(256)
void k_cvt8(const float* __restrict__ in, bf16* __restrict__ out, long n8)
{
    const long id = (long)blockIdx.x * 256 + threadIdx.x;
    if (id >= n8) return;
    const float4 a = ((const float4*)in)[id * 2];
    const float4 b = ((const float4*)in)[id * 2 + 1];
    short8 o;
    o[0] = f2b(a.x); o[1] = f2b(a.y); o[2] = f2b(a.z); o[3] = f2b(a.w);
    o[4] = f2b(b.x); o[5] = f2b(b.y); o[6] = f2b(b.z); o[7] = f2b(b.w);
    ((short8*)out)[id] = o;
}

// ---------------------------------------------------------------------------
// W [K,N] fp32 -> WT [N,K] bf16   (writes coalesced, reads strided; tiny)
// ---------------------------------------------------------------------------
__global__ void k_transpose(const float* __restrict__ W, bf16* __restrict__ WT,
                            int K, int N)
{
    const int id = blockIdx.x * 256 + threadIdx.x;
    if (id >= K * N) return;
    const int n = id / K, k = id % K;
    WT[id] = __float2bfloat16(W[(long)k * N + n]);
}

// ---------------------------------------------------------------------------
// GEMM: C[M,N] = A[M,K] @ W[K,N], W given pre-transposed as BT[N,K] (bf16).
// m97 structure: 128x128 tile, BK=64, 4 waves (2x2 of 64x64), 16x16x32 MFMA.
// EPI: 0 = none (fp32 out), 1 = elu+1 (bf16), 2 = *escale (bf16), 3 = relu (bf16)
// ---------------------------------------------------------------------------
template<int EPI>
__global__ __launch_bounds__(256)
void k_gemm(const bf16* __restrict__ A, const bf16* __restrict__ BT,
            void* __restrict__ C, int M, int N, int K, float escale)
{
    __shared__ __attribute__((aligned(16))) bf16 Asm[128 * 64];
    __shared__ __attribute__((aligned(16))) bf16 Bsm[128 * 64];
    const int tid  = threadIdx.x;
    const int wave = tid >> 6, lane = tid & 63;
    const int wm = wave >> 1, wn = wave & 1;
    const long row0 = (long)blockIdx.x * 128;
    const long col0 = (long)blockIdx.y * 128;

    f32x4 acc[4][4] = {};

    const int lr = lane >> 3;        // row within an 8-row staging group
    const int lc = (lane & 7) * 8;   // elem offset within 64-wide k window

    for (int kt = 0; kt < K; kt += 64) {
        #pragma unroll
        for (int i = 0; i < 4; ++i) {
            const int grp = wave * 4 + i;            // 0..15
            const long r  = grp * 8 + lr;
            async16(A  + (row0 + r) * K + kt + lc, &Asm[grp * 512]);
            async16(BT + (col0 + r) * K + kt + lc, &Bsm[grp * 512]);
        }
        __syncthreads();
        #pragma unroll
        for (int ks = 0; ks < 2; ++ks) {
            short8 a[4], b[4];
            #pragma unroll
            for (int m = 0; m < 4; ++m)
                a[m] = *(const short8*)&Asm[(wm*64 + m*16 + (lane & 15))*64 + ks*32 + (lane>>4)*8];
            #pragma unroll
            for (int n = 0; n < 4; ++n)
                b[n] = *(const short8*)&Bsm[(wn*64 + n*16 + (lane & 15))*64 + ks*32 + (lane>>4)*8];
            #pragma unroll
            for (int m = 0; m < 4; ++m)
                #pragma unroll
                for (int n = 0; n < 4; ++n)
                    acc[m][n] = __builtin_amdgcn_mfma_f32_16x16x32_bf16(a[m], b[n], acc[m][n], 0, 0, 0);
        }
        __syncthreads();
    }

    // epilogue: C/D layout col=lane&15, row=(lane>>4)*4+reg  [m89]
    #pragma unroll
    for (int m = 0; m < 4; ++m) {
        #pragma unroll
        for (int n = 0; n < 4; ++n) {
            #pragma unroll
            for (int r = 0; r < 4; ++r) {
                const long row = row0 + wm*64 + m*16 + (lane >> 4)*4 + r;
                const long col = col0 + wn*64 + n*16 + (lane & 15);
                float v = acc[m][n][r];
                if constexpr (EPI == 1) v = v > 0.f ? v + 1.f : __expf(v); // elu(v)+1
                if constexpr (EPI == 2) v *= escale;
                if constexpr (EPI == 3) v = v > 0.f ? v : 0.f;
                if constexpr (EPI == 0) ((float*)C)[row * N + col] = v;
                else                    ((bf16*)C)[row * N + col] = __float2bfloat16(v);
            }
        }
    }
}

// ---------------------------------------------------------------------------
// Partial KV / Ksum. Grid (128 s-chunks, 4 batches), 64 rows per block.
// Thread: h = t>>5; dg = (t&31)>>2 (4 d's); vg = t&3 (8 v's). acc[4][8].
// LDS staged bf16 via global_load_lds; vector ds_reads (b64 k / b128 v).
// partKV bf16 [c][n][h*1024 + d*32 + v]; partKs f32 [c][n][256].
// ---------------------------------------------------------------------------
__global__ __launch_bounds__(256)
void k_kv2(const bf16* __restrict__ Kb, const bf16* __restrict__ Vb,
           bf16* __restrict__ partKV, float* __restrict__ partKs)
{
    __shared__ __attribute__((aligned(16))) bf16 Kls[16 * 256];
    __shared__ __attribute__((aligned(16))) bf16 Vls[16 * 256];
    const int c = blockIdx.x;   // 0..127
    const int n = blockIdx.y;   // 0..3
    const int t = threadIdx.x;
    const int w = t >> 6, lane = t & 63;
    const int h = t >> 5, tt = t & 31, dg = tt >> 2, vg = tt & 3;
    float acc[4][8] = {};
    float ksacc[4] = {};
    const long base = ((long)n * 8192 + (long)c * 64) * 256;

    for (int s0 = 0; s0 < 64; s0 += 16) {
        #pragma unroll
        for (int p = 0; p < 2; ++p) {
            const int ch = p * 4 + w;   // 8 wave-chunks of 512 elems
            async16(Kb + base + s0 * 256 + ch * 512 + lane * 8, &Kls[ch * 512]);
            async16(Vb + base + s0 * 256 + ch * 512 + lane * 8, &Vls[ch * 512]);
        }
        __syncthreads();
        #pragma unroll
        for (int i = 0; i < 16; ++i) {
            const bf16x4 kk = *(const bf16x4*)&Kls[i * 256 + h * 32 + dg * 4];
            const short8 vv = *(const short8*)&Vls[i * 256 + h * 32 + vg * 8];
            float kf[4], vf[8];
            #pragma unroll
            for (int j = 0; j < 4; ++j) { kf[j] = b2f(kk[j]); ksacc[j] += kf[j]; }
            #pragma unroll
            for (int u = 0; u < 8; ++u) vf[u] = b2f(vv[u]);
            #pragma unroll
            for (int j = 0; j < 4; ++j)
                #pragma unroll
                for (int u = 0; u < 8; ++u) acc[j][u] += kf[j] * vf[u];
        }
        __syncthreads();
    }

    const long pb = (long)(c * 4 + n) * 8192 + h * 1024;
    #pragma unroll
    for (int j = 0; j < 4; ++j) {
        short8 o;
        #pragma unroll
        for (int u = 0; u < 8; ++u) o[u] = f2b(acc[j][u]);
        *(short8*)&partKV[pb + (dg * 4 + j) * 32 + vg * 8] = o;
    }
    if (vg == 0) {
        f32x4 o4;
        #pragma unroll
        for (int j = 0; j < 4; ++j) o4[j] = ksacc[j];
        *(f32x4*)&partKs[(c * 4 + n) * 256 + h * 32 + dg * 4] = o4;
    }
}

// ---------------------------------------------------------------------------
// Reduce partials -> KVaug bf16 [n][h][d=32][48]: cols 0-31 KV, 32 Ksum, rest 0
// Grid: 32 blocks (n*8+h); thread: d = t>>3, vg = t&7 (4 v's).
// ---------------------------------------------------------------------------
__global__ __launch_bounds__(256)
void k_kv_reduce2(const bf16* __restrict__ partKV, const float* __restrict__ partKs,
                  bf16* __restrict__ KVb)
{
    const int b = blockIdx.x;
    const int n = b >> 3, h = b & 7;
    const int t = threadIdx.x;
    const int d = t >> 3, vg = t & 7;
    float s[4] = {};
    for (int c = 0; c < 128; ++c) {
        const bf16x4 p = *(const bf16x4*)&partKV[(long)(c * 4 + n) * 8192 + h * 1024 + d * 32 + vg * 4];
        #pragma unroll
        for (int j = 0; j < 4; ++j) s[j] += b2f(p[j]);
    }
    bf16* dst = KVb + ((long)n * 8 + h) * 1536 + d * 48;
    bf16x4 o;
    #pragma unroll
    for (int j = 0; j < 4; ++j) o[j] = f2b(s[j]);
    *(bf16x4*)&dst[vg * 4] = o;
    if (vg == 0) {
        float ks = 0.f;
        for (int c = 0; c < 128; ++c) ks += partKs[(c * 4 + n) * 256 + h * 32 + d];
        short8 z0 = {};
        z0[0] = f2b(ks);
        *(short8*)&dst[32] = z0;           // cols 32..39 (32 = Ksum)
        short8 zz = {};
        *(short8*)&dst[40] = zz;           // cols 40..47
    }
}

// ---------------------------------------------------------------------------
// MFMA attention: per (n,h): [Q][L,32] @ KVaug[32][48] (cols 0-31 = KV,
// col 32 = Ksum -> z). msg1 = acc * S/(z+eps). Block = 128 rows, 4 waves.
// ---------------------------------------------------------------------------
__global__ __launch_bounds__(256)
void k_attn2(const bf16* __restrict__ Qb, const bf16* __restrict__ KVb,
             bf16* __restrict__ msg1)
{
    __shared__ __attribute__((aligned(16))) bf16 kvls[12288];
    const int n = blockIdx.y;
    const long row0 = (long)n * 8192 + (long)blockIdx.x * 128;
    const int t = threadIdx.x, w = t >> 6, lane = t & 63;
    const int lr = lane & 15, lg = lane >> 4;

    #pragma unroll
    for (int p = 0; p < 6; ++p) {
        const int ch = p * 4 + w;   // 24 wave-chunks of 512 elems
        async16(KVb + (long)n * 12288 + ch * 512 + lane * 8, &kvls[ch * 512]);
    }
    __syncthreads();

    for (int h = 0; h < 8; ++h) {
        short8 b0, b1, bz;
        #pragma unroll
        for (int j = 0; j < 8; ++j) {
            const int drow = h * 1536 + (lg * 8 + j) * 48;
            b0[j] = __builtin_bit_cast(short, kvls[drow + lr]);
            b1[j] = __builtin_bit_cast(short, kvls[drow + 16 + lr]);
            bz[j] = __builtin_bit_cast(short, kvls[drow + 32 + lr]);
        }
        #pragma unroll
        for (int m = 0; m < 2; ++m) {
            const long rbase = row0 + w * 32 + m * 16;
            const short8 a = *(const short8*)&Qb[(rbase + lr) * 256 + h * 32 + lg * 8];
            f32x4 a0 = {}, a1 = {}, az = {};
            a0 = __builtin_amdgcn_mfma_f32_16x16x32_bf16(a, b0, a0, 0, 0, 0);
            a1 = __builtin_amdgcn_mfma_f32_16x16x32_bf16(a, b1, a1, 0, 0, 0);
            az = __builtin_amdgcn_mfma_f32_16x16x32_bf16(a, bz, az, 0, 0, 0);
            #pragma unroll
            for (int r = 0; r < 4; ++r) {
                const float z   = __shfl(az[r], lane & 48);  // col 32 holders
                const float inv = 8192.f / (z + EPS_ATTN);
                const long row = rbase + lg * 4 + r;
                bf16* o = msg1 + row * 256 + h * 32;
                o[lr]      = __float2bfloat16(a0[r] * inv);
                o[16 + lr] = __float2bfloat16(a1[r] * inv);
            }
        }
    }
}

// ---------------------------------------------------------------------------
// LayerNorm helpers (one 256-thread block per row of 256)
// ---------------------------------------------------------------------------
__device__ __forceinline__ float block_reduce_sum(float v, float* ws)
{
    #pragma unroll
    for (int o = 32; o > 0; o >>= 1) v += __shfl_xor(v, o);
    const int wave = threadIdx.x >> 6;
    __syncthreads();
    if ((threadIdx.x & 63) == 0) ws[wave] = v;
    __syncthreads();
    return ws[0] + ws[1] + ws[2] + ws[3];
}

// LN1 + build hcat = [x_bf | LN(msgm)] (bf16 [32768,512])
__global__ __launch_bounds__(256)
void k_ln1_hcat(const float* __restrict__ msgm, const float* __restrict__ g,
                const float* __restrict__ b, const bf16* __restrict__ xb,
                bf16* __restrict__ hcat)
{
    __shared__ float ws[4];
    const long row = blockIdx.x;
    const int t = threadIdx.x;
    const float v  = msgm[row * 256 + t];
    const float mu = block_reduce_sum(v, ws) * (1.f / 256.f);
    const float dv = v - mu;
    const float var = block_reduce_sum(dv * dv, ws) * (1.f / 256.f);
    const float y = dv * rsqrtf(var + EPS_LN) * g[t] + b[t];
    hcat[row * 512 + t]       = xb[row * 256 + t];
    hcat[row * 512 + 256 + t] = __float2bfloat16(y);
}

// LN2 + residual: out = x + LN(msg2)   (fp32)
__global__ __launch_bounds__(256)
void k_ln2_res(const float* __restrict__ msg2, const float* __restrict__ g,
               const float* __restrict__ b, const float* __restrict__ x,
               float* __restrict__ out)
{
    __shared__ float ws[4];
    const long row = blockIdx.x;
    const int t = threadIdx.x;
    const float v  = msg2[row * 256 + t];
    const float mu = block_reduce_sum(v, ws) * (1.f / 256.f);
    const float dv = v - mu;
    const float var = block_reduce_sum(dv * dv, ws) * (1.f / 256.f);
    const float y = dv * rsqrtf(var + EPS_LN) * g[t] + b[t];
    out[row * 256 + t] = x[row * 256 + t] + y;
}

// ---------------------------------------------------------------------------
extern "C" void kernel_launch(void* const* d_in, const int* in_sizes, int n_in,
                              void* d_out, int out_size, void* d_ws, size_t ws_size,
                              hipStream_t stream)
{
    const float* x      = (const float*)d_in[0];
    const float* source = (const float*)d_in[1];
    const float* Wq     = (const float*)d_in[2];
    const float* Wk     = (const float*)d_in[3];
    const float* Wv     = (const float*)d_in[4];
    const float* Wm     = (const float*)d_in[5];
    const float* W1     = (const float*)d_in[6];
    const float* W2     = (const float*)d_in[7];
    const float* g1     = (const float*)d_in[8];
    const float* b1     = (const float*)d_in[9];
    const float* g2     = (const float*)d_in[10];
    const float* b2     = (const float*)d_in[11];
    float* out = (float*)d_out;

    const long M = 32768;                 // N*L = 4*8192 rows
    const size_t U = 32768ull * 256ull;   // one activation slot (elements)
    char* w = (char*)d_ws;

    // slot layout (each slot = U bf16 elements = 16 MB); lifetimes verified:
    bf16* x_bf  = (bf16*)(w + 0 * U * 2);
    bf16* s_bf  = (bf16*)(w + 1 * U * 2);
    bf16* Q_bf  = (bf16*)(w + 2 * U * 2);
    bf16* K_bf  = (bf16*)(w + 3 * U * 2);
    bf16* V_bf  = (bf16*)(w + 4 * U * 2);
    bf16* msg1  = (bf16*)(w + 5 * U * 2);
    float* msgm = (float*)(w + 3 * U * 2);  // slots 3-4 (K,V dead after k_kv2)
    bf16* hcat  = (bf16*)(w + 1 * U * 2);   // slots 1-2 (src,Q dead)
    bf16* t_bf  = (bf16*)(w + 3 * U * 2);   // slots 3-4 (msgm dead after ln1)
    float* msg2 = (float*)(w + 5 * U * 2);  // slots 5-6 (msg1 dead)

    char* wx = w + 7 * U * 2;
    bf16* WqT = (bf16*)wx; wx += 65536 * 2;
    bf16* WkT = (bf16*)wx; wx += 65536 * 2;
    bf16* WvT = (bf16*)wx; wx += 65536 * 2;
    bf16* WmT = (bf16*)wx; wx += 65536 * 2;
    bf16* W1T = (bf16*)wx; wx += 262144 * 2;
    bf16* W2T = (bf16*)wx; wx += 131072 * 2;
    bf16* partKV = (bf16*)wx; wx += 4194304 * 2;   // 128 chunks x 4 n x 8192
    float* partKs = (float*)wx; wx += 131072 * 4;  // 128 x 4 x 256
    bf16* KVb    = (bf16*)wx; wx += 49152 * 2;     // [n][h][32][48] aug

    const dim3 blk(256);

    // 1) converts + weight transposes
    k_cvt8<<<4096, blk, 0, stream>>>(x, x_bf, M * 256 / 8);
    k_cvt8<<<4096, blk, 0, stream>>>(source, s_bf, M * 256 / 8);
    k_transpose<<<256,  blk, 0, stream>>>(Wq, WqT, 256, 256);
    k_transpose<<<256,  blk, 0, stream>>>(Wk, WkT, 256, 256);
    k_transpose<<<256,  blk, 0, stream>>>(Wv, WvT, 256, 256);
    k_transpose<<<256,  blk, 0, stream>>>(Wm, WmT, 256, 256);
    k_transpose<<<1024, blk, 0, stream>>>(W1, W1T, 512, 512);
    k_transpose<<<512,  blk, 0, stream>>>(W2, W2T, 512, 256);

    // 2) projections: Q = fmap(x@Wq), K = fmap(src@Wk), Vn = (src@Wv)/S
    k_gemm<1><<<dim3(256, 2), blk, 0, stream>>>(x_bf, WqT, Q_bf, 32768, 256, 256, 0.f);
    k_gemm<1><<<dim3(256, 2), blk, 0, stream>>>(s_bf, WkT, K_bf, 32768, 256, 256, 0.f);
    k_gemm<2><<<dim3(256, 2), blk, 0, stream>>>(s_bf, WvT, V_bf, 32768, 256, 256, 1.f / 8192.f);

    // 3) KV = sum_s K^T Vn per head (+Ksum) -> KVaug bf16
    k_kv2<<<dim3(128, 4), blk, 0, stream>>>(K_bf, V_bf, partKV, partKs);
    k_kv_reduce2<<<32, blk, 0, stream>>>(partKV, partKs, KVb);

    // 4) MFMA attention matvec -> msg1
    k_attn2<<<dim3(64, 4), blk, 0, stream>>>(Q_bf, KVb, msg1);

    // 5) merge GEMM (fp32 out), LN1 + hcat
    k_gemm<0><<<dim3(256, 2), blk, 0, stream>>>(msg1, WmT, msgm, 32768, 256, 256, 0.f);
    k_ln1_hcat<<<32768, blk, 0, stream>>>(msgm, g1, b1, x_bf, hcat);

    // 6) MLP: t = relu(hcat@W1), msg2 = t@W2 (fp32)
    k_gemm<3><<<dim3(256, 4), blk, 0, stream>>>(hcat, W1T, t_bf, 32768, 512, 512, 0.f);
    k_gemm<0><<<dim3(256, 2), blk, 0, stream>>>(t_bf, W2T, msg2, 32768, 256, 512, 0.f);

    // 7) LN2 + residual
    k_ln2_res<<<32768, blk, 0, stream>>>(msg2, g2, b2, x, out);
}

// Round 4
// 196.205 us; speedup vs baseline: 1.3778x; 1.1648x over previous
//
#include <hip/hip_runtime.h>
#include <hip/hip_bf16.h>
#include <stdint.h>

typedef __hip_bfloat16 bf16;
typedef __attribute__((ext_vector_type(8))) short short8;
typedef __attribute__((ext_vector_type(4))) short bf16x4;
typedef __attribute__((ext_vector_type(4))) float f32x4;

#define EPS_ATTN 1e-6f
#define EPS_LN   1e-5f

__device__ __forceinline__ float b2f(short s) {
    return __builtin_bit_cast(float, (unsigned)((unsigned short)s) << 16);
}
__device__ __forceinline__ short f2b(float f) {
    return __builtin_bit_cast(short, __float2bfloat16(f));
}

// ---------------------------------------------------------------------------
// async global->LDS, 16B per lane. LDS dest = wave-uniform base + lane*16.
// ---------------------------------------------------------------------------
__device__ __forceinline__ void async16(const void* g, void* l) {
    __builtin_amdgcn_global_load_lds(
        (const __attribute__((address_space(1))) void*)g,
        (__attribute__((address_space(3))) void*)l,
        16, 0, 0);
}

// ---------------------------------------------------------------------------
// fp32 -> bf16 convert, 8 elements/thread
// ---------------------------------------------------------------------------
__global__ __launch_bounds__(256)
void k_cvt8(const float* __restrict__ in, bf16* __restrict__ out, long n8)
{
    const long id = (long)blockIdx.x * 256 + threadIdx.x;
    if (id >= n8) return;
    const float4 a = ((const float4*)in)[id * 2];
    const float4 b = ((const float4*)in)[id * 2 + 1];
    short8 o;
    o[0] = f2b(a.x); o[1] = f2b(a.y); o[2] = f2b(a.z); o[3] = f2b(a.w);
    o[4] = f2b(b.x); o[5] = f2b(b.y); o[6] = f2b(b.z); o[7] = f2b(b.w);
    ((short8*)out)[id] = o;
}

// ---------------------------------------------------------------------------
// Tiled transpose: W [K,N] fp32 -> WT [N,K] bf16. 64x64 tiles via LDS,
// coalesced on both sides. Grid (K/64, N/64), 256 threads.
// ---------------------------------------------------------------------------
__global__ __launch_bounds__(256)
void k_transpose_t(const float* __restrict__ W, bf16* __restrict__ WT,
                   int K, int N)
{
    __shared__ float tile[64][65];
    const int k0 = blockIdx.x * 64, n0 = blockIdx.y * 64;
    const int ty = threadIdx.x >> 4, tx = threadIdx.x & 15;
    #pragma unroll
    for (int i = 0; i < 4; ++i) {
        const int k = ty + i * 16;
        const float4 v = *(const float4*)&W[(long)(k0 + k) * N + n0 + tx * 4];
        tile[k][tx * 4 + 0] = v.x; tile[k][tx * 4 + 1] = v.y;
        tile[k][tx * 4 + 2] = v.z; tile[k][tx * 4 + 3] = v.w;
    }
    __syncthreads();
    #pragma unroll
    for (int i = 0; i < 4; ++i) {
        const int n = ty + i * 16;
        bf16x4 o;
        #pragma unroll
        for (int j = 0; j < 4; ++j) o[j] = f2b(tile[tx * 4 + j][n]);
        *(bf16x4*)&WT[(long)(n0 + n) * K + k0 + tx * 4] = o;
    }
}

// ---------------------------------------------------------------------------
// GEMM: C[M,N] = A[M,K] @ W[K,N], W pre-transposed as BT[N,K] (bf16).
// 128x128 tile, BK=64, 4 waves, 16x16x32 MFMA.
// EPI: 1 = elu+1 (bf16), 2 = *escale (bf16)
// ---------------------------------------------------------------------------
template<int EPI>
__global__ __launch_bounds__(256)
void k_gemm(const bf16* __restrict__ A, const bf16* __restrict__ BT,
            void* __restrict__ C, int M, int N, int K, float escale)
{
    __shared__ __attribute__((aligned(16))) bf16 Asm[128 * 64];
    __shared__ __attribute__((aligned(16))) bf16 Bsm[128 * 64];
    const int tid  = threadIdx.x;
    const int wave = tid >> 6, lane = tid & 63;
    const int wm = wave >> 1, wn = wave & 1;
    const long row0 = (long)blockIdx.x * 128;
    const long col0 = (long)blockIdx.y * 128;

    f32x4 acc[4][4] = {};

    const int lr = lane >> 3;
    const int lc = (lane & 7) * 8;

    for (int kt = 0; kt < K; kt += 64) {
        #pragma unroll
        for (int i = 0; i < 4; ++i) {
            const int grp = wave * 4 + i;
            const long r  = grp * 8 + lr;
            async16(A  + (row0 + r) * K + kt + lc, &Asm[grp * 512]);
            async16(BT + (col0 + r) * K + kt + lc, &Bsm[grp * 512]);
        }
        __syncthreads();
        #pragma unroll
        for (int ks = 0; ks < 2; ++ks) {
            short8 a[4], b[4];
            #pragma unroll
            for (int m = 0; m < 4; ++m)
                a[m] = *(const short8*)&Asm[(wm*64 + m*16 + (lane & 15))*64 + ks*32 + (lane>>4)*8];
            #pragma unroll
            for (int n = 0; n < 4; ++n)
                b[n] = *(const short8*)&Bsm[(wn*64 + n*16 + (lane & 15))*64 + ks*32 + (lane>>4)*8];
            #pragma unroll
            for (int m = 0; m < 4; ++m)
                #pragma unroll
                for (int n = 0; n < 4; ++n)
                    acc[m][n] = __builtin_amdgcn_mfma_f32_16x16x32_bf16(a[m], b[n], acc[m][n], 0, 0, 0);
        }
        __syncthreads();
    }

    #pragma unroll
    for (int m = 0; m < 4; ++m) {
        #pragma unroll
        for (int n = 0; n < 4; ++n) {
            #pragma unroll
            for (int r = 0; r < 4; ++r) {
                const long row = row0 + wm*64 + m*16 + (lane >> 4)*4 + r;
                const long col = col0 + wn*64 + n*16 + (lane & 15);
                float v = acc[m][n][r];
                if constexpr (EPI == 1) v = v > 0.f ? v + 1.f : __expf(v);
                if constexpr (EPI == 2) v *= escale;
                ((bf16*)C)[row * N + col] = __float2bfloat16(v);
            }
        }
    }
}

// ---------------------------------------------------------------------------
// W1 GEMM with split-K A (virtual hcat = [A0 | A1], both [M,256] bf16):
// t_bf = relu([A0|A1] @ W1), W1T [512][512]. Grid (M/128, 4), 256 thr.
// ---------------------------------------------------------------------------
__global__ __launch_bounds__(256)
void k_gemmW1(const bf16* __restrict__ A0, const bf16* __restrict__ A1,
              const bf16* __restrict__ BT, bf16* __restrict__ C)
{
    __shared__ __attribute__((aligned(16))) bf16 Asm[128 * 64];
    __shared__ __attribute__((aligned(16))) bf16 Bsm[128 * 64];
    const int tid  = threadIdx.x;
    const int wave = tid >> 6, lane = tid & 63;
    const int wm = wave >> 1, wn = wave & 1;
    const long row0 = (long)blockIdx.x * 128;
    const long col0 = (long)blockIdx.y * 128;

    f32x4 acc[4][4] = {};
    const int lr = lane >> 3;
    const int lc = (lane & 7) * 8;

    for (int kt = 0; kt < 512; kt += 64) {
        const bf16* Asrc = (kt < 256) ? A0 : A1;
        const int kk = kt & 255;
        #pragma unroll
        for (int i = 0; i < 4; ++i) {
            const int grp = wave * 4 + i;
            const long r  = grp * 8 + lr;
            async16(Asrc + (row0 + r) * 256 + kk + lc, &Asm[grp * 512]);
            async16(BT   + (col0 + r) * 512 + kt + lc, &Bsm[grp * 512]);
        }
        __syncthreads();
        #pragma unroll
        for (int ks = 0; ks < 2; ++ks) {
            short8 a[4], b[4];
            #pragma unroll
            for (int m = 0; m < 4; ++m)
                a[m] = *(const short8*)&Asm[(wm*64 + m*16 + (lane & 15))*64 + ks*32 + (lane>>4)*8];
            #pragma unroll
            for (int n = 0; n < 4; ++n)
                b[n] = *(const short8*)&Bsm[(wn*64 + n*16 + (lane & 15))*64 + ks*32 + (lane>>4)*8];
            #pragma unroll
            for (int m = 0; m < 4; ++m)
                #pragma unroll
                for (int n = 0; n < 4; ++n)
                    acc[m][n] = __builtin_amdgcn_mfma_f32_16x16x32_bf16(a[m], b[n], acc[m][n], 0, 0, 0);
        }
        __syncthreads();
    }

    #pragma unroll
    for (int m = 0; m < 4; ++m) {
        #pragma unroll
        for (int n = 0; n < 4; ++n) {
            #pragma unroll
            for (int r = 0; r < 4; ++r) {
                const long row = row0 + wm*64 + m*16 + (lane >> 4)*4 + r;
                const long col = col0 + wn*64 + n*16 + (lane & 15);
                const float v = acc[m][n][r];
                C[row * 512 + col] = __float2bfloat16(v > 0.f ? v : 0.f);
            }
        }
    }
}

// ---------------------------------------------------------------------------
// Fused GEMM + row-LayerNorm (N=256 = full tile width). 64x256 tile,
// 8 waves (2 row-groups x 4 col-groups), 512 threads, grid M/64.
// RES=false: out = bf16 LN(A@B)           (merge + LN1 -> msgln)
// RES=true : out = fp32 x + LN(A@B)       (W2 + LN2 + residual)
// ---------------------------------------------------------------------------
template<int K, bool RES>
__global__ __launch_bounds__(512)
void k_gemm_ln(const bf16* __restrict__ A, const bf16* __restrict__ BT,
               const float* __restrict__ g, const float* __restrict__ b,
               const float* __restrict__ xres, void* __restrict__ out)
{
    __shared__ __attribute__((aligned(16))) bf16 Asm[64 * 64];
    __shared__ __attribute__((aligned(16))) bf16 Bsm[256 * 64];
    __shared__ float lnS[4][64];
    __shared__ float lnQ[4][64];
    const int t = threadIdx.x, w = t >> 6, lane = t & 63;
    const int wm = w >> 2, wn = w & 3;
    const long row0 = (long)blockIdx.x * 64;
    const int lr = lane >> 3, lc = (lane & 7) * 8;
    const int lg = lane >> 4, l15 = lane & 15;

    f32x4 acc[2][4] = {};

    for (int kt = 0; kt < K; kt += 64) {
        async16(A + (row0 + w * 8 + lr) * K + kt + lc, &Asm[w * 512]);
        #pragma unroll
        for (int i = 0; i < 4; ++i) {
            const int ch = i * 8 + w;
            async16(BT + (long)(ch * 8 + lr) * K + kt + lc, &Bsm[ch * 512]);
        }
        __syncthreads();
        #pragma unroll
        for (int ks = 0; ks < 2; ++ks) {
            short8 a[2], bb[4];
            #pragma unroll
            for (int m = 0; m < 2; ++m)
                a[m] = *(const short8*)&Asm[(wm*32 + m*16 + l15)*64 + ks*32 + lg*8];
            #pragma unroll
            for (int n = 0; n < 4; ++n)
                bb[n] = *(const short8*)&Bsm[(wn*64 + n*16 + l15)*64 + ks*32 + lg*8];
            #pragma unroll
            for (int m = 0; m < 2; ++m)
                #pragma unroll
                for (int n = 0; n < 4; ++n)
                    acc[m][n] = __builtin_amdgcn_mfma_f32_16x16x32_bf16(a[m], bb[n], acc[m][n], 0, 0, 0);
        }
        __syncthreads();
    }

    // ---- row LN: per-row sum/sumsq -> 16-lane butterfly -> cross-wave LDS
    #pragma unroll
    for (int m = 0; m < 2; ++m) {
        #pragma unroll
        for (int r = 0; r < 4; ++r) {
            float ls = 0.f, lq = 0.f;
            #pragma unroll
            for (int n = 0; n < 4; ++n) {
                const float v = acc[m][n][r];
                ls += v; lq += v * v;
            }
            #pragma unroll
            for (int o = 1; o < 16; o <<= 1) {
                ls += __shfl_xor(ls, o);
                lq += __shfl_xor(lq, o);
            }
            if (l15 == 0) {
                const int row = wm * 32 + m * 16 + lg * 4 + r;
                lnS[wn][row] = ls;
                lnQ[wn][row] = lq;
            }
        }
    }
    __syncthreads();

    float gv[4], bv[4];
    #pragma unroll
    for (int n = 0; n < 4; ++n) {
        const int col = wn * 64 + n * 16 + l15;
        gv[n] = g[col]; bv[n] = b[col];
    }
    #pragma unroll
    for (int m = 0; m < 2; ++m) {
        #pragma unroll
        for (int r = 0; r < 4; ++r) {
            const int row = wm * 32 + m * 16 + lg * 4 + r;
            const float S  = lnS[0][row] + lnS[1][row] + lnS[2][row] + lnS[3][row];
            const float Qq = lnQ[0][row] + lnQ[1][row] + lnQ[2][row] + lnQ[3][row];
            const float mean = S * (1.f / 256.f);
            const float var  = Qq * (1.f / 256.f) - mean * mean;
            const float rstd = rsqrtf(var + EPS_LN);
            const long grow = row0 + row;
            #pragma unroll
            for (int n = 0; n < 4; ++n) {
                const int col = wn * 64 + n * 16 + l15;
                const float y = (acc[m][n][r] - mean) * rstd * gv[n] + bv[n];
                if constexpr (RES)
                    ((float*)out)[grow * 256 + col] = xres[grow * 256 + col] + y;
                else
                    ((bf16*)out)[grow * 256 + col] = __float2bfloat16(y);
            }
        }
    }
}

// ---------------------------------------------------------------------------
// Partial KV / Ksum. Grid (128 s-chunks, 4 batches), 64 rows per block.
// ---------------------------------------------------------------------------
__global__ __launch_bounds__(256)
void k_kv2(const bf16* __restrict__ Kb, const bf16* __restrict__ Vb,
           bf16* __restrict__ partKV, float* __restrict__ partKs)
{
    __shared__ __attribute__((aligned(16))) bf16 Kls[16 * 256];
    __shared__ __attribute__((aligned(16))) bf16 Vls[16 * 256];
    const int c = blockIdx.x;
    const int n = blockIdx.y;
    const int t = threadIdx.x;
    const int w = t >> 6, lane = t & 63;
    const int h = t >> 5, tt = t & 31, dg = tt >> 2, vg = tt & 3;
    float acc[4][8] = {};
    float ksacc[4] = {};
    const long base = ((long)n * 8192 + (long)c * 64) * 256;

    for (int s0 = 0; s0 < 64; s0 += 16) {
        #pragma unroll
        for (int p = 0; p < 2; ++p) {
            const int ch = p * 4 + w;
            async16(Kb + base + s0 * 256 + ch * 512 + lane * 8, &Kls[ch * 512]);
            async16(Vb + base + s0 * 256 + ch * 512 + lane * 8, &Vls[ch * 512]);
        }
        __syncthreads();
        #pragma unroll
        for (int i = 0; i < 16; ++i) {
            const bf16x4 kk = *(const bf16x4*)&Kls[i * 256 + h * 32 + dg * 4];
            const short8 vv = *(const short8*)&Vls[i * 256 + h * 32 + vg * 8];
            float kf[4], vf[8];
            #pragma unroll
            for (int j = 0; j < 4; ++j) { kf[j] = b2f(kk[j]); ksacc[j] += kf[j]; }
            #pragma unroll
            for (int u = 0; u < 8; ++u) vf[u] = b2f(vv[u]);
            #pragma unroll
            for (int j = 0; j < 4; ++j)
                #pragma unroll
                for (int u = 0; u < 8; ++u) acc[j][u] += kf[j] * vf[u];
        }
        __syncthreads();
    }

    const long pb = (long)(c * 4 + n) * 8192 + h * 1024;
    #pragma unroll
    for (int j = 0; j < 4; ++j) {
        short8 o;
        #pragma unroll
        for (int u = 0; u < 8; ++u) o[u] = f2b(acc[j][u]);
        *(short8*)&partKV[pb + (dg * 4 + j) * 32 + vg * 8] = o;
    }
    if (vg == 0) {
        f32x4 o4;
        #pragma unroll
        for (int j = 0; j < 4; ++j) o4[j] = ksacc[j];
        *(f32x4*)&partKs[(c * 4 + n) * 256 + h * 32 + dg * 4] = o4;
    }
}

// ---------------------------------------------------------------------------
// Reduce partials -> KVaug bf16 [n][h][32][48]: cols 0-31 KV, 32 Ksum
// ---------------------------------------------------------------------------
__global__ __launch_bounds__(256)
void k_kv_reduce2(const bf16* __restrict__ partKV, const float* __restrict__ partKs,
                  bf16* __restrict__ KVb)
{
    const int b = blockIdx.x;
    const int n = b >> 3, h = b & 7;
    const int t = threadIdx.x;
    const int d = t >> 3, vg = t & 7;
    float s[4] = {};
    #pragma unroll 4
    for (int c = 0; c < 128; ++c) {
        const bf16x4 p = *(const bf16x4*)&partKV[(long)(c * 4 + n) * 8192 + h * 1024 + d * 32 + vg * 4];
        #pragma unroll
        for (int j = 0; j < 4; ++j) s[j] += b2f(p[j]);
    }
    bf16* dst = KVb + ((long)n * 8 + h) * 1536 + d * 48;
    bf16x4 o;
    #pragma unroll
    for (int j = 0; j < 4; ++j) o[j] = f2b(s[j]);
    *(bf16x4*)&dst[vg * 4] = o;
    if (vg == 0) {
        float ks = 0.f;
        #pragma unroll 4
        for (int c = 0; c < 128; ++c) ks += partKs[(c * 4 + n) * 256 + h * 32 + d];
        short8 z0 = {};
        z0[0] = f2b(ks);
        *(short8*)&dst[32] = z0;
        short8 zz = {};
        *(short8*)&dst[40] = zz;
    }
}

// ---------------------------------------------------------------------------
// MFMA attention: per (n,h): Q[L,32] @ KVaug[32][48]; col 32 = Ksum -> z.
// ---------------------------------------------------------------------------
__global__ __launch_bounds__(256)
void k_attn2(const bf16* __restrict__ Qb, const bf16* __restrict__ KVb,
             bf16* __restrict__ msg1)
{
    __shared__ __attribute__((aligned(16))) bf16 kvls[12288];
    const int n = blockIdx.y;
    const long row0 = (long)n * 8192 + (long)blockIdx.x * 128;
    const int t = threadIdx.x, w = t >> 6, lane = t & 63;
    const int lr = lane & 15, lg = lane >> 4;

    #pragma unroll
    for (int p = 0; p < 6; ++p) {
        const int ch = p * 4 + w;
        async16(KVb + (long)n * 12288 + ch * 512 + lane * 8, &kvls[ch * 512]);
    }
    __syncthreads();

    for (int h = 0; h < 8; ++h) {
        short8 b0, b1, bz;
        #pragma unroll
        for (int j = 0; j < 8; ++j) {
            const int drow = h * 1536 + (lg * 8 + j) * 48;
            b0[j] = __builtin_bit_cast(short, kvls[drow + lr]);
            b1[j] = __builtin_bit_cast(short, kvls[drow + 16 + lr]);
            bz[j] = __builtin_bit_cast(short, kvls[drow + 32 + lr]);
        }
        #pragma unroll
        for (int m = 0; m < 2; ++m) {
            const long rbase = row0 + w * 32 + m * 16;
            const short8 a = *(const short8*)&Qb[(rbase + lr) * 256 + h * 32 + lg * 8];
            f32x4 a0 = {}, a1 = {}, az = {};
            a0 = __builtin_amdgcn_mfma_f32_16x16x32_bf16(a, b0, a0, 0, 0, 0);
            a1 = __builtin_amdgcn_mfma_f32_16x16x32_bf16(a, b1, a1, 0, 0, 0);
            az = __builtin_amdgcn_mfma_f32_16x16x32_bf16(a, bz, az, 0, 0, 0);
            #pragma unroll
            for (int r = 0; r < 4; ++r) {
                const float z   = __shfl(az[r], lane & 48);
                const float inv = 8192.f / (z + EPS_ATTN);
                const long row = rbase + lg * 4 + r;
                bf16* o = msg1 + row * 256 + h * 32;
                o[lr]      = __float2bfloat16(a0[r] * inv);
                o[16 + lr] = __float2bfloat16(a1[r] * inv);
            }
        }
    }
}

// ---------------------------------------------------------------------------
extern "C" void kernel_launch(void* const* d_in, const int* in_sizes, int n_in,
                              void* d_out, int out_size, void* d_ws, size_t ws_size,
                              hipStream_t stream)
{
    const float* x      = (const float*)d_in[0];
    const float* source = (const float*)d_in[1];
    const float* Wq     = (const float*)d_in[2];
    const float* Wk     = (const float*)d_in[3];
    const float* Wv     = (const float*)d_in[4];
    const float* Wm     = (const float*)d_in[5];
    const float* W1     = (const float*)d_in[6];
    const float* W2     = (const float*)d_in[7];
    const float* g1     = (const float*)d_in[8];
    const float* b1     = (const float*)d_in[9];
    const float* g2     = (const float*)d_in[10];
    const float* b2     = (const float*)d_in[11];
    float* out = (float*)d_out;

    const long M = 32768;
    const size_t U = 32768ull * 256ull;
    char* w = (char*)d_ws;

    // slots (16 MB each); lifetimes:
    bf16* x_bf  = (bf16*)(w + 0 * U * 2);   // alive through W1 gemm
    bf16* s_bf  = (bf16*)(w + 1 * U * 2);   // dead after K,V gemms
    bf16* Q_bf  = (bf16*)(w + 2 * U * 2);   // dead after attn
    bf16* K_bf  = (bf16*)(w + 3 * U * 2);   // dead after k_kv2
    bf16* V_bf  = (bf16*)(w + 4 * U * 2);   // dead after k_kv2
    bf16* msg1  = (bf16*)(w + 5 * U * 2);   // dead after merge gemm
    bf16* msgln = (bf16*)(w + 1 * U * 2);   // reuse slot 1
    bf16* t_bf  = (bf16*)(w + 3 * U * 2);   // slots 3-4 ([32768,512])

    char* wx = w + 7 * U * 2;
    bf16* WqT = (bf16*)wx; wx += 65536 * 2;
    bf16* WkT = (bf16*)wx; wx += 65536 * 2;
    bf16* WvT = (bf16*)wx; wx += 65536 * 2;
    bf16* WmT = (bf16*)wx; wx += 65536 * 2;
    bf16* W1T = (bf16*)wx; wx += 262144 * 2;
    bf16* W2T = (bf16*)wx; wx += 131072 * 2;
    bf16* partKV = (bf16*)wx; wx += 4194304 * 2;
    float* partKs = (float*)wx; wx += 131072 * 4;
    bf16* KVb    = (bf16*)wx; wx += 49152 * 2;

    const dim3 blk(256);

    // 1) converts + weight transposes (tiled)
    k_cvt8<<<4096, blk, 0, stream>>>(x, x_bf, M * 256 / 8);
    k_cvt8<<<4096, blk, 0, stream>>>(source, s_bf, M * 256 / 8);
    k_transpose_t<<<dim3(4, 4),  blk, 0, stream>>>(Wq, WqT, 256, 256);
    k_transpose_t<<<dim3(4, 4),  blk, 0, stream>>>(Wk, WkT, 256, 256);
    k_transpose_t<<<dim3(4, 4),  blk, 0, stream>>>(Wv, WvT, 256, 256);
    k_transpose_t<<<dim3(4, 4),  blk, 0, stream>>>(Wm, WmT, 256, 256);
    k_transpose_t<<<dim3(8, 8),  blk, 0, stream>>>(W1, W1T, 512, 512);
    k_transpose_t<<<dim3(8, 4),  blk, 0, stream>>>(W2, W2T, 512, 256);

    // 2) projections
    k_gemm<1><<<dim3(256, 2), blk, 0, stream>>>(x_bf, WqT, Q_bf, 32768, 256, 256, 0.f);
    k_gemm<1><<<dim3(256, 2), blk, 0, stream>>>(s_bf, WkT, K_bf, 32768, 256, 256, 0.f);
    k_gemm<2><<<dim3(256, 2), blk, 0, stream>>>(s_bf, WvT, V_bf, 32768, 256, 256, 1.f / 8192.f);

    // 3) KV + Ksum -> KVaug
    k_kv2<<<dim3(128, 4), blk, 0, stream>>>(K_bf, V_bf, partKV, partKs);
    k_kv_reduce2<<<32, blk, 0, stream>>>(partKV, partKs, KVb);

    // 4) MFMA attention -> msg1
    k_attn2<<<dim3(64, 4), blk, 0, stream>>>(Q_bf, KVb, msg1);

    // 5) merge GEMM + LN1 fused -> msgln (bf16)
    k_gemm_ln<256, false><<<512, dim3(512), 0, stream>>>(msg1, WmT, g1, b1, nullptr, msgln);

    // 6) MLP: t = relu([x_bf|msgln] @ W1) ; then W2 + LN2 + residual fused
    k_gemmW1<<<dim3(256, 4), blk, 0, stream>>>(x_bf, msgln, W1T, t_bf);
    k_gemm_ln<512, true><<<512, dim3(512), 0, stream>>>(t_bf, W2T, g2, b2, x, out);
}

// Round 5
// 185.157 us; speedup vs baseline: 1.4600x; 1.0597x over previous
//
#include <hip/hip_runtime.h>
#include <hip/hip_bf16.h>
#include <stdint.h>

typedef __hip_bfloat16 bf16;
typedef __attribute__((ext_vector_type(8))) short short8;
typedef __attribute__((ext_vector_type(4))) short bf16x4;
typedef __attribute__((ext_vector_type(4))) float f32x4;

#define EPS_ATTN 1e-6f
#define EPS_LN   1e-5f

__device__ __forceinline__ float b2f(short s) {
    return __builtin_bit_cast(float, (unsigned)((unsigned short)s) << 16);
}
__device__ __forceinline__ short f2b(float f) {
    return __builtin_bit_cast(short, __float2bfloat16(f));
}

// ---------------------------------------------------------------------------
// async global->LDS, 16B per lane. LDS dest = wave-uniform base + lane*16;
// global source address IS per-lane (m173).
// ---------------------------------------------------------------------------
__device__ __forceinline__ void async16(const void* g, void* l) {
    __builtin_amdgcn_global_load_lds(
        (const __attribute__((address_space(1))) void*)g,
        (__attribute__((address_space(3))) void*)l,
        16, 0, 0);
}

// ---------------------------------------------------------------------------
// fp32 -> bf16 convert, both tensors in one launch (grid.y picks tensor)
// ---------------------------------------------------------------------------
__global__ __launch_bounds__(256)
void k_cvt8x2(const float* __restrict__ inA, const float* __restrict__ inB,
              bf16* __restrict__ outA, bf16* __restrict__ outB, long n8)
{
    const float* in = blockIdx.y ? inB : inA;
    bf16* out       = blockIdx.y ? outB : outA;
    const long id = (long)blockIdx.x * 256 + threadIdx.x;
    if (id >= n8) return;
    const float4 a = ((const float4*)in)[id * 2];
    const float4 b = ((const float4*)in)[id * 2 + 1];
    short8 o;
    o[0] = f2b(a.x); o[1] = f2b(a.y); o[2] = f2b(a.z); o[3] = f2b(a.w);
    o[4] = f2b(b.x); o[5] = f2b(b.y); o[6] = f2b(b.z); o[7] = f2b(b.w);
    ((short8*)out)[id] = o;
}

// ---------------------------------------------------------------------------
// All 6 weight transposes in ONE kernel. 64x64 fp32->bf16 tiles via LDS.
// blocks 0-15 Wq | 16-31 Wk | 32-47 Wv | 48-63 Wm | 64-127 W1 | 128-159 W2
// ---------------------------------------------------------------------------
__device__ __forceinline__ void tr_tile(const float* __restrict__ W,
                                        bf16* __restrict__ WT,
                                        int K, int N, int k0, int n0,
                                        float (*tile)[65])
{
    const int ty = threadIdx.x >> 4, tx = threadIdx.x & 15;
    #pragma unroll
    for (int i = 0; i < 4; ++i) {
        const int k = ty + i * 16;
        const float4 v = *(const float4*)&W[(long)(k0 + k) * N + n0 + tx * 4];
        tile[k][tx * 4 + 0] = v.x; tile[k][tx * 4 + 1] = v.y;
        tile[k][tx * 4 + 2] = v.z; tile[k][tx * 4 + 3] = v.w;
    }
    __syncthreads();
    #pragma unroll
    for (int i = 0; i < 4; ++i) {
        const int n = ty + i * 16;
        bf16x4 o;
        #pragma unroll
        for (int j = 0; j < 4; ++j) o[j] = f2b(tile[tx * 4 + j][n]);
        *(bf16x4*)&WT[(long)(n0 + n) * K + k0 + tx * 4] = o;
    }
}

__global__ __launch_bounds__(256)
void k_transpose_all(const float* __restrict__ Wq, const float* __restrict__ Wk,
                     const float* __restrict__ Wv, const float* __restrict__ Wm,
                     const float* __restrict__ W1, const float* __restrict__ W2,
                     bf16* __restrict__ WqT, bf16* __restrict__ WkT,
                     bf16* __restrict__ WvT, bf16* __restrict__ WmT,
                     bf16* __restrict__ W1T, bf16* __restrict__ W2T)
{
    __shared__ float tile[64][65];
    const int b = blockIdx.x;
    const float* W; bf16* WT; int K, N, local;
    if      (b < 16)  { W = Wq; WT = WqT; K = 256; N = 256; local = b; }
    else if (b < 32)  { W = Wk; WT = WkT; K = 256; N = 256; local = b - 16; }
    else if (b < 48)  { W = Wv; WT = WvT; K = 256; N = 256; local = b - 32; }
    else if (b < 64)  { W = Wm; WT = WmT; K = 256; N = 256; local = b - 48; }
    else if (b < 128) { W = W1; WT = W1T; K = 512; N = 512; local = b - 64; }
    else              { W = W2; WT = W2T; K = 512; N = 256; local = b - 128; }
    const int tk = K / 64;
    const int k0 = (local % tk) * 64, n0 = (local / tk) * 64;
    tr_tile(W, WT, K, N, k0, n0, tile);
}

// ---------------------------------------------------------------------------
// GEMM: C[M,N] = A[M,K] @ W[K,N], W pre-transposed as BT[N,K] (bf16).
// 128x128 tile, BK=64, 4 waves, 16x16x32 MFMA.
// EPI: 1 = elu+1 (bf16), 2 = *escale (bf16)
// ---------------------------------------------------------------------------
template<int EPI>
__global__ __launch_bounds__(256)
void k_gemm(const bf16* __restrict__ A, const bf16* __restrict__ BT,
            void* __restrict__ C, int M, int N, int K, float escale)
{
    __shared__ __attribute__((aligned(16))) bf16 Asm[128 * 64];
    __shared__ __attribute__((aligned(16))) bf16 Bsm[128 * 64];
    const int tid  = threadIdx.x;
    const int wave = tid >> 6, lane = tid & 63;
    const int wm = wave >> 1, wn = wave & 1;
    const long row0 = (long)blockIdx.x * 128;
    const long col0 = (long)blockIdx.y * 128;

    f32x4 acc[4][4] = {};

    const int lr = lane >> 3;
    const int lc = (lane & 7) * 8;

    for (int kt = 0; kt < K; kt += 64) {
        #pragma unroll
        for (int i = 0; i < 4; ++i) {
            const int grp = wave * 4 + i;
            const long r  = grp * 8 + lr;
            async16(A  + (row0 + r) * K + kt + lc, &Asm[grp * 512]);
            async16(BT + (col0 + r) * K + kt + lc, &Bsm[grp * 512]);
        }
        __syncthreads();
        #pragma unroll
        for (int ks = 0; ks < 2; ++ks) {
            short8 a[4], b[4];
            #pragma unroll
            for (int m = 0; m < 4; ++m)
                a[m] = *(const short8*)&Asm[(wm*64 + m*16 + (lane & 15))*64 + ks*32 + (lane>>4)*8];
            #pragma unroll
            for (int n = 0; n < 4; ++n)
                b[n] = *(const short8*)&Bsm[(wn*64 + n*16 + (lane & 15))*64 + ks*32 + (lane>>4)*8];
            #pragma unroll
            for (int m = 0; m < 4; ++m)
                #pragma unroll
                for (int n = 0; n < 4; ++n)
                    acc[m][n] = __builtin_amdgcn_mfma_f32_16x16x32_bf16(a[m], b[n], acc[m][n], 0, 0, 0);
        }
        __syncthreads();
    }

    #pragma unroll
    for (int m = 0; m < 4; ++m) {
        #pragma unroll
        for (int n = 0; n < 4; ++n) {
            #pragma unroll
            for (int r = 0; r < 4; ++r) {
                const long row = row0 + wm*64 + m*16 + (lane >> 4)*4 + r;
                const long col = col0 + wn*64 + n*16 + (lane & 15);
                float v = acc[m][n][r];
                if constexpr (EPI == 1) v = v > 0.f ? v + 1.f : __expf(v);
                if constexpr (EPI == 2) v *= escale;
                ((bf16*)C)[row * N + col] = __float2bfloat16(v);
            }
        }
    }
}

// ---------------------------------------------------------------------------
// Fused GEMM + row-LayerNorm (N=256 = full tile width). 64x256 tile,
// 8 waves, 512 threads, grid M/64.  out = bf16 LN(A@B)  (merge + LN1)
// ---------------------------------------------------------------------------
__global__ __launch_bounds__(512)
void k_gemm_ln(const bf16* __restrict__ A, const bf16* __restrict__ BT,
               const float* __restrict__ g, const float* __restrict__ b,
               bf16* __restrict__ out)
{
    __shared__ __attribute__((aligned(16))) bf16 Asm[64 * 64];
    __shared__ __attribute__((aligned(16))) bf16 Bsm[256 * 64];
    __shared__ float lnS[4][64];
    __shared__ float lnQ[4][64];
    const int t = threadIdx.x, w = t >> 6, lane = t & 63;
    const int wm = w >> 2, wn = w & 3;
    const long row0 = (long)blockIdx.x * 64;
    const int lr = lane >> 3, lc = (lane & 7) * 8;
    const int lg = lane >> 4, l15 = lane & 15;

    f32x4 acc[2][4] = {};

    for (int kt = 0; kt < 256; kt += 64) {
        async16(A + (row0 + w * 8 + lr) * 256 + kt + lc, &Asm[w * 512]);
        #pragma unroll
        for (int i = 0; i < 4; ++i) {
            const int ch = i * 8 + w;
            async16(BT + (long)(ch * 8 + lr) * 256 + kt + lc, &Bsm[ch * 512]);
        }
        __syncthreads();
        #pragma unroll
        for (int ks = 0; ks < 2; ++ks) {
            short8 a[2], bb[4];
            #pragma unroll
            for (int m = 0; m < 2; ++m)
                a[m] = *(const short8*)&Asm[(wm*32 + m*16 + l15)*64 + ks*32 + lg*8];
            #pragma unroll
            for (int n = 0; n < 4; ++n)
                bb[n] = *(const short8*)&Bsm[(wn*64 + n*16 + l15)*64 + ks*32 + lg*8];
            #pragma unroll
            for (int m = 0; m < 2; ++m)
                #pragma unroll
                for (int n = 0; n < 4; ++n)
                    acc[m][n] = __builtin_amdgcn_mfma_f32_16x16x32_bf16(a[m], bb[n], acc[m][n], 0, 0, 0);
        }
        __syncthreads();
    }

    #pragma unroll
    for (int m = 0; m < 2; ++m) {
        #pragma unroll
        for (int r = 0; r < 4; ++r) {
            float ls = 0.f, lq = 0.f;
            #pragma unroll
            for (int n = 0; n < 4; ++n) {
                const float v = acc[m][n][r];
                ls += v; lq += v * v;
            }
            #pragma unroll
            for (int o = 1; o < 16; o <<= 1) {
                ls += __shfl_xor(ls, o);
                lq += __shfl_xor(lq, o);
            }
            if (l15 == 0) {
                const int row = wm * 32 + m * 16 + lg * 4 + r;
                lnS[wn][row] = ls;
                lnQ[wn][row] = lq;
            }
        }
    }
    __syncthreads();

    float gv[4], bv[4];
    #pragma unroll
    for (int n = 0; n < 4; ++n) {
        const int col = wn * 64 + n * 16 + l15;
        gv[n] = g[col]; bv[n] = b[col];
    }
    #pragma unroll
    for (int m = 0; m < 2; ++m) {
        #pragma unroll
        for (int r = 0; r < 4; ++r) {
            const int row = wm * 32 + m * 16 + lg * 4 + r;
            const float S  = lnS[0][row] + lnS[1][row] + lnS[2][row] + lnS[3][row];
            const float Qq = lnQ[0][row] + lnQ[1][row] + lnQ[2][row] + lnQ[3][row];
            const float mean = S * (1.f / 256.f);
            const float var  = Qq * (1.f / 256.f) - mean * mean;
            const float rstd = rsqrtf(var + EPS_LN);
            const long grow = row0 + row;
            #pragma unroll
            for (int n = 0; n < 4; ++n) {
                const int col = wn * 64 + n * 16 + l15;
                const float y = (acc[m][n][r] - mean) * rstd * gv[n] + bv[n];
                out[grow * 256 + col] = __float2bfloat16(y);
            }
        }
    }
}

// ---------------------------------------------------------------------------
// Fused MLP: out = x + LN2( relu([x_bf|msgln] @ W1) @ W2 ).
// Block = 64 rows, 512 thr, 8 waves. A (64x512 bf16, 64KB) staged once into
// LDS via async16 with pre-swizzled source (chunk ^= row&7); W1T/W2T B-frags
// read register-direct from L2. t = relu(.) overwrites the A LDS (swizzled).
// ---------------------------------------------------------------------------
__global__ __launch_bounds__(512)
void k_mlp(const bf16* __restrict__ xb, const bf16* __restrict__ msgln,
           const bf16* __restrict__ W1T, const bf16* __restrict__ W2T,
           const float* __restrict__ g, const float* __restrict__ b,
           const float* __restrict__ xres, float* __restrict__ out)
{
    __shared__ __attribute__((aligned(16))) bf16 Atl[64 * 512];  // A, then t
    __shared__ float lnS[4][64];
    __shared__ float lnQ[4][64];
    const int t = threadIdx.x, w = t >> 6, lane = t & 63;
    const long row0 = (long)blockIdx.x * 64;
    const int lg = lane >> 4, l15 = lane & 15;

    // ---- stage A = [xb | msgln] (64 rows x 512 k), physical chunk p holds
    // logical chunk c = p ^ (row&7)  (XOR stays within 8-chunk groups)
    #pragma unroll
    for (int i = 0; i < 8; ++i) {
        const int row = i * 8 + w;
        const int c = lane ^ (row & 7);
        const bf16* src = (c < 32) ? (xb    + (row0 + row) * 256 + c * 8)
                                   : (msgln + (row0 + row) * 256 + (c - 32) * 8);
        async16(src, &Atl[row * 512]);
    }
    __syncthreads();

    // ---- phase A: per wave, cols w*64..w*64+63 of t, all 64 rows
    const int col0 = w * 64;
    f32x4 acc[4][4] = {};
    for (int kt = 0; kt < 512; kt += 64) {
        short8 aa[4][2], bb[4][2];
        #pragma unroll
        for (int ks = 0; ks < 2; ++ks) {
            #pragma unroll
            for (int n = 0; n < 4; ++n)
                bb[n][ks] = *(const short8*)&W1T[(long)(col0 + n*16 + l15) * 512 + kt + ks*32 + lg*8];
            #pragma unroll
            for (int m = 0; m < 4; ++m) {
                const int row  = m * 16 + l15;
                const int kc   = kt + ks*32 + lg*8;
                const int phys = (kc >> 3) ^ (row & 7);
                aa[m][ks] = *(const short8*)&Atl[row * 512 + phys * 8];
            }
        }
        #pragma unroll
        for (int ks = 0; ks < 2; ++ks)
            #pragma unroll
            for (int m = 0; m < 4; ++m)
                #pragma unroll
                for (int n = 0; n < 4; ++n)
                    acc[m][n] = __builtin_amdgcn_mfma_f32_16x16x32_bf16(aa[m][ks], bb[n][ks], acc[m][n], 0, 0, 0);
    }
    __syncthreads();                       // all A reads done

    // ---- t = relu(acc) -> Atl (same swizzle)
    #pragma unroll
    for (int m = 0; m < 4; ++m) {
        #pragma unroll
        for (int n = 0; n < 4; ++n) {
            #pragma unroll
            for (int r = 0; r < 4; ++r) {
                const int row = m * 16 + lg * 4 + r;
                const int col = col0 + n * 16 + l15;
                float v = acc[m][n][r]; v = v > 0.f ? v : 0.f;
                const int phys = (col >> 3) ^ (row & 7);
                Atl[row * 512 + phys * 8 + (col & 7)] = __float2bfloat16(v);
            }
        }
    }
    __syncthreads();                       // t visible

    // ---- phase B: msg2 = t @ W2 (K=512), wave = (wm rowgrp, wn colgrp)
    const int wm = w >> 2, wn = w & 3;
    f32x4 acc2[2][4] = {};
    for (int kt = 0; kt < 512; kt += 64) {
        short8 aa[2][2], bb[4][2];
        #pragma unroll
        for (int ks = 0; ks < 2; ++ks) {
            #pragma unroll
            for (int n = 0; n < 4; ++n)
                bb[n][ks] = *(const short8*)&W2T[(long)(wn*64 + n*16 + l15) * 512 + kt + ks*32 + lg*8];
            #pragma unroll
            for (int m = 0; m < 2; ++m) {
                const int row  = wm * 32 + m * 16 + l15;
                const int kc   = kt + ks*32 + lg*8;
                const int phys = (kc >> 3) ^ (row & 7);
                aa[m][ks] = *(const short8*)&Atl[row * 512 + phys * 8];
            }
        }
        #pragma unroll
        for (int ks = 0; ks < 2; ++ks)
            #pragma unroll
            for (int m = 0; m < 2; ++m)
                #pragma unroll
                for (int n = 0; n < 4; ++n)
                    acc2[m][n] = __builtin_amdgcn_mfma_f32_16x16x32_bf16(aa[m][ks], bb[n][ks], acc2[m][n], 0, 0, 0);
    }

    // ---- LN2 + residual
    #pragma unroll
    for (int m = 0; m < 2; ++m) {
        #pragma unroll
        for (int r = 0; r < 4; ++r) {
            float ls = 0.f, lq = 0.f;
            #pragma unroll
            for (int n = 0; n < 4; ++n) {
                const float v = acc2[m][n][r];
                ls += v; lq += v * v;
            }
            #pragma unroll
            for (int o = 1; o < 16; o <<= 1) {
                ls += __shfl_xor(ls, o);
                lq += __shfl_xor(lq, o);
            }
            if (l15 == 0) {
                const int row = wm * 32 + m * 16 + lg * 4 + r;
                lnS[wn][row] = ls;
                lnQ[wn][row] = lq;
            }
        }
    }
    __syncthreads();

    float gv[4], bv[4];
    #pragma unroll
    for (int n = 0; n < 4; ++n) {
        const int col = wn * 64 + n * 16 + l15;
        gv[n] = g[col]; bv[n] = b[col];
    }
    #pragma unroll
    for (int m = 0; m < 2; ++m) {
        #pragma unroll
        for (int r = 0; r < 4; ++r) {
            const int row = wm * 32 + m * 16 + lg * 4 + r;
            const float S  = lnS[0][row] + lnS[1][row] + lnS[2][row] + lnS[3][row];
            const float Qq = lnQ[0][row] + lnQ[1][row] + lnQ[2][row] + lnQ[3][row];
            const float mean = S * (1.f / 256.f);
            const float var  = Qq * (1.f / 256.f) - mean * mean;
            const float rstd = rsqrtf(var + EPS_LN);
            const long grow = row0 + row;
            #pragma unroll
            for (int n = 0; n < 4; ++n) {
                const int col = wn * 64 + n * 16 + l15;
                const float y = (acc2[m][n][r] - mean) * rstd * gv[n] + bv[n];
                out[grow * 256 + col] = xres[grow * 256 + col] + y;
            }
        }
    }
}

// ---------------------------------------------------------------------------
// Partial KV / Ksum. Grid (128 s-chunks, 4 batches), 64 rows per block.
// ---------------------------------------------------------------------------
__global__ __launch_bounds__(256)
void k_kv2(const bf16* __restrict__ Kb, const bf16* __restrict__ Vb,
           bf16* __restrict__ partKV, float* __restrict__ partKs)
{
    __shared__ __attribute__((aligned(16))) bf16 Kls[16 * 256];
    __shared__ __attribute__((aligned(16))) bf16 Vls[16 * 256];
    const int c = blockIdx.x;
    const int n = blockIdx.y;
    const int t = threadIdx.x;
    const int w = t >> 6, lane = t & 63;
    const int h = t >> 5, tt = t & 31, dg = tt >> 2, vg = tt & 3;
    float acc[4][8] = {};
    float ksacc[4] = {};
    const long base = ((long)n * 8192 + (long)c * 64) * 256;

    for (int s0 = 0; s0 < 64; s0 += 16) {
        #pragma unroll
        for (int p = 0; p < 2; ++p) {
            const int ch = p * 4 + w;
            async16(Kb + base + s0 * 256 + ch * 512 + lane * 8, &Kls[ch * 512]);
            async16(Vb + base + s0 * 256 + ch * 512 + lane * 8, &Vls[ch * 512]);
        }
        __syncthreads();
        #pragma unroll
        for (int i = 0; i < 16; ++i) {
            const bf16x4 kk = *(const bf16x4*)&Kls[i * 256 + h * 32 + dg * 4];
            const short8 vv = *(const short8*)&Vls[i * 256 + h * 32 + vg * 8];
            float kf[4], vf[8];
            #pragma unroll
            for (int j = 0; j < 4; ++j) { kf[j] = b2f(kk[j]); ksacc[j] += kf[j]; }
            #pragma unroll
            for (int u = 0; u < 8; ++u) vf[u] = b2f(vv[u]);
            #pragma unroll
            for (int j = 0; j < 4; ++j)
                #pragma unroll
                for (int u = 0; u < 8; ++u) acc[j][u] += kf[j] * vf[u];
        }
        __syncthreads();
    }

    const long pb = (long)(c * 4 + n) * 8192 + h * 1024;
    #pragma unroll
    for (int j = 0; j < 4; ++j) {
        short8 o;
        #pragma unroll
        for (int u = 0; u < 8; ++u) o[u] = f2b(acc[j][u]);
        *(short8*)&partKV[pb + (dg * 4 + j) * 32 + vg * 8] = o;
    }
    if (vg == 0) {
        f32x4 o4;
        #pragma unroll
        for (int j = 0; j < 4; ++j) o4[j] = ksacc[j];
        *(f32x4*)&partKs[(c * 4 + n) * 256 + h * 32 + dg * 4] = o4;
    }
}

// ---------------------------------------------------------------------------
// KV reduce stage 1: 128 -> 8 partials. Grid 256 = (n<<6)|(h<<3)|c8.
// ---------------------------------------------------------------------------
__global__ __launch_bounds__(256)
void k_kvred1(const bf16* __restrict__ partKV, const float* __restrict__ partKs,
              bf16* __restrict__ part2, float* __restrict__ part2Ks)
{
    const int bid = blockIdx.x;
    const int c8 = bid & 7, h = (bid >> 3) & 7, n = bid >> 6;
    const int t = threadIdx.x;
    const int d = t >> 3, vg = t & 7;
    float s[4] = {};
    #pragma unroll
    for (int i = 0; i < 16; ++i) {
        const int c = c8 * 16 + i;
        const bf16x4 p = *(const bf16x4*)&partKV[(long)(c * 4 + n) * 8192 + h * 1024 + d * 32 + vg * 4];
        #pragma unroll
        for (int j = 0; j < 4; ++j) s[j] += b2f(p[j]);
    }
    bf16x4 o;
    #pragma unroll
    for (int j = 0; j < 4; ++j) o[j] = f2b(s[j]);
    *(bf16x4*)&part2[(long)(c8 * 4 + n) * 8192 + h * 1024 + d * 32 + vg * 4] = o;
    if (vg == 0) {
        float ks = 0.f;
        #pragma unroll
        for (int i = 0; i < 16; ++i) {
            const int c = c8 * 16 + i;
            ks += partKs[(c * 4 + n) * 256 + h * 32 + d];
        }
        part2Ks[(c8 * 4 + n) * 256 + h * 32 + d] = ks;
    }
}

// ---------------------------------------------------------------------------
// KV reduce stage 2: 8 partials -> KVaug bf16 [n][h][32][48] (col 32 = Ksum)
// ---------------------------------------------------------------------------
__global__ __launch_bounds__(256)
void k_kvred2(const bf16* __restrict__ part2, const float* __restrict__ part2Ks,
              bf16* __restrict__ KVb)
{
    const int b = blockIdx.x;
    const int n = b >> 3, h = b & 7;
    const int t = threadIdx.x;
    const int d = t >> 3, vg = t & 7;
    float s[4] = {};
    #pragma unroll
    for (int c8 = 0; c8 < 8; ++c8) {
        const bf16x4 p = *(const bf16x4*)&part2[(long)(c8 * 4 + n) * 8192 + h * 1024 + d * 32 + vg * 4];
        #pragma unroll
        for (int j = 0; j < 4; ++j) s[j] += b2f(p[j]);
    }
    bf16* dst = KVb + ((long)n * 8 + h) * 1536 + d * 48;
    bf16x4 o;
    #pragma unroll
    for (int j = 0; j < 4; ++j) o[j] = f2b(s[j]);
    *(bf16x4*)&dst[vg * 4] = o;
    if (vg == 0) {
        float ks = 0.f;
        #pragma unroll
        for (int c8 = 0; c8 < 8; ++c8) ks += part2Ks[(c8 * 4 + n) * 256 + h * 32 + d];
        short8 z0 = {};
        z0[0] = f2b(ks);
        *(short8*)&dst[32] = z0;
        short8 zz = {};
        *(short8*)&dst[40] = zz;
    }
}

// ---------------------------------------------------------------------------
// MFMA attention: per (n,h): Q[L,32] @ KVaug[32][48]; col 32 = Ksum -> z.
// ---------------------------------------------------------------------------
__global__ __launch_bounds__(256)
void k_attn2(const bf16* __restrict__ Qb, const bf16* __restrict__ KVb,
             bf16* __restrict__ msg1)
{
    __shared__ __attribute__((aligned(16))) bf16 kvls[12288];
    const int n = blockIdx.y;
    const long row0 = (long)n * 8192 + (long)blockIdx.x * 128;
    const int t = threadIdx.x, w = t >> 6, lane = t & 63;
    const int lr = lane & 15, lg = lane >> 4;

    #pragma unroll
    for (int p = 0; p < 6; ++p) {
        const int ch = p * 4 + w;
        async16(KVb + (long)n * 12288 + ch * 512 + lane * 8, &kvls[ch * 512]);
    }
    __syncthreads();

    for (int h = 0; h < 8; ++h) {
        short8 b0, b1, bz;
        #pragma unroll
        for (int j = 0; j < 8; ++j) {
            const int drow = h * 1536 + (lg * 8 + j) * 48;
            b0[j] = __builtin_bit_cast(short, kvls[drow + lr]);
            b1[j] = __builtin_bit_cast(short, kvls[drow + 16 + lr]);
            bz[j] = __builtin_bit_cast(short, kvls[drow + 32 + lr]);
        }
        #pragma unroll
        for (int m = 0; m < 2; ++m) {
            const long rbase = row0 + w * 32 + m * 16;
            const short8 a = *(const short8*)&Qb[(rbase + lr) * 256 + h * 32 + lg * 8];
            f32x4 a0 = {}, a1 = {}, az = {};
            a0 = __builtin_amdgcn_mfma_f32_16x16x32_bf16(a, b0, a0, 0, 0, 0);
            a1 = __builtin_amdgcn_mfma_f32_16x16x32_bf16(a, b1, a1, 0, 0, 0);
            az = __builtin_amdgcn_mfma_f32_16x16x32_bf16(a, bz, az, 0, 0, 0);
            #pragma unroll
            for (int r = 0; r < 4; ++r) {
                const float z   = __shfl(az[r], lane & 48);
                const float inv = 8192.f / (z + EPS_ATTN);
                const long row = rbase + lg * 4 + r;
                bf16* o = msg1 + row * 256 + h * 32;
                o[lr]      = __float2bfloat16(a0[r] * inv);
                o[16 + lr] = __float2bfloat16(a1[r] * inv);
            }
        }
    }
}

// ---------------------------------------------------------------------------
extern "C" void kernel_launch(void* const* d_in, const int* in_sizes, int n_in,
                              void* d_out, int out_size, void* d_ws, size_t ws_size,
                              hipStream_t stream)
{
    const float* x      = (const float*)d_in[0];
    const float* source = (const float*)d_in[1];
    const float* Wq     = (const float*)d_in[2];
    const float* Wk     = (const float*)d_in[3];
    const float* Wv     = (const float*)d_in[4];
    const float* Wm     = (const float*)d_in[5];
    const float* W1     = (const float*)d_in[6];
    const float* W2     = (const float*)d_in[7];
    const float* g1     = (const float*)d_in[8];
    const float* b1     = (const float*)d_in[9];
    const float* g2     = (const float*)d_in[10];
    const float* b2     = (const float*)d_in[11];
    float* out = (float*)d_out;

    const long M = 32768;
    const size_t U = 32768ull * 256ull;
    char* w = (char*)d_ws;

    // slots (16 MB each); lifetimes:
    bf16* x_bf  = (bf16*)(w + 0 * U * 2);   // alive through k_mlp
    bf16* s_bf  = (bf16*)(w + 1 * U * 2);   // dead after K,V gemms
    bf16* Q_bf  = (bf16*)(w + 2 * U * 2);   // dead after attn
    bf16* K_bf  = (bf16*)(w + 3 * U * 2);   // dead after k_kv2
    bf16* V_bf  = (bf16*)(w + 4 * U * 2);   // dead after k_kv2
    bf16* msg1  = (bf16*)(w + 5 * U * 2);   // dead after merge gemm
    bf16* msgln = (bf16*)(w + 1 * U * 2);   // reuse slot 1, alive through k_mlp

    char* wx = w + 7 * U * 2;
    bf16* WqT = (bf16*)wx; wx += 65536 * 2;
    bf16* WkT = (bf16*)wx; wx += 65536 * 2;
    bf16* WvT = (bf16*)wx; wx += 65536 * 2;
    bf16* WmT = (bf16*)wx; wx += 65536 * 2;
    bf16* W1T = (bf16*)wx; wx += 262144 * 2;
    bf16* W2T = (bf16*)wx; wx += 131072 * 2;
    bf16* partKV = (bf16*)wx; wx += 4194304 * 2;   // 128 x 4 x 8192
    float* partKs = (float*)wx; wx += 131072 * 4;  // 128 x 4 x 256
    bf16* part2  = (bf16*)wx; wx += 262144 * 2;    // 8 x 4 x 8192
    float* part2Ks = (float*)wx; wx += 8192 * 4;   // 8 x 4 x 256
    bf16* KVb    = (bf16*)wx; wx += 49152 * 2;     // [n][h][32][48]

    const dim3 blk(256);

    // 1) converts (one launch) + all weight transposes (one launch)
    k_cvt8x2<<<dim3(4096, 2), blk, 0, stream>>>(x, source, x_bf, s_bf, M * 256 / 8);
    k_transpose_all<<<160, blk, 0, stream>>>(Wq, Wk, Wv, Wm, W1, W2,
                                             WqT, WkT, WvT, WmT, W1T, W2T);

    // 2) projections
    k_gemm<1><<<dim3(256, 2), blk, 0, stream>>>(x_bf, WqT, Q_bf, 32768, 256, 256, 0.f);
    k_gemm<1><<<dim3(256, 2), blk, 0, stream>>>(s_bf, WkT, K_bf, 32768, 256, 256, 0.f);
    k_gemm<2><<<dim3(256, 2), blk, 0, stream>>>(s_bf, WvT, V_bf, 32768, 256, 256, 1.f / 8192.f);

    // 3) KV + Ksum -> KVaug (2-stage deterministic reduce)
    k_kv2<<<dim3(128, 4), blk, 0, stream>>>(K_bf, V_bf, partKV, partKs);
    k_kvred1<<<256, blk, 0, stream>>>(partKV, partKs, part2, part2Ks);
    k_kvred2<<<32, blk, 0, stream>>>(part2, part2Ks, KVb);

    // 4) MFMA attention -> msg1
    k_attn2<<<dim3(64, 4), blk, 0, stream>>>(Q_bf, KVb, msg1);

    // 5) merge GEMM + LN1 fused -> msgln (bf16)
    k_gemm_ln<<<512, dim3(512), 0, stream>>>(msg1, WmT, g1, b1, msgln);

    // 6) fused MLP: out = x + LN2(relu([x_bf|msgln]@W1)@W2)
    k_mlp<<<512, dim3(512), 0, stream>>>(x_bf, msgln, W1T, W2T, g2, b2, x, out);
}

// Round 6
// 162.807 us; speedup vs baseline: 1.6604x; 1.1373x over previous
//
#include <hip/hip_runtime.h>
#include <hip/hip_bf16.h>
#include <stdint.h>

typedef __hip_bfloat16 bf16;
typedef __attribute__((ext_vector_type(8))) short short8;
typedef __attribute__((ext_vector_type(4))) short bf16x4;
typedef __attribute__((ext_vector_type(4))) float f32x4;

#define EPS_ATTN 1e-6f
#define EPS_LN   1e-5f

__device__ __forceinline__ float b2f(short s) {
    return __builtin_bit_cast(float, (unsigned)((unsigned short)s) << 16);
}
__device__ __forceinline__ short f2b(float f) {
    return __builtin_bit_cast(short, __float2bfloat16(f));
}

// ---------------------------------------------------------------------------
// async global->LDS, 16B per lane. LDS dest = wave-uniform base + lane*16.
// ---------------------------------------------------------------------------
__device__ __forceinline__ void async16(const void* g, void* l) {
    __builtin_amdgcn_global_load_lds(
        (const __attribute__((address_space(1))) void*)g,
        (__attribute__((address_space(3))) void*)l,
        16, 0, 0);
}

// ---------------------------------------------------------------------------
// fp32 -> bf16 convert, both tensors in one launch (grid.y picks tensor)
// ---------------------------------------------------------------------------
__global__ __launch_bounds__(256)
void k_cvt8x2(const float* __restrict__ inA, const float* __restrict__ inB,
              bf16* __restrict__ outA, bf16* __restrict__ outB, long n8)
{
    const float* in = blockIdx.y ? inB : inA;
    bf16* out       = blockIdx.y ? outB : outA;
    const long id = (long)blockIdx.x * 256 + threadIdx.x;
    if (id >= n8) return;
    const float4 a = ((const float4*)in)[id * 2];
    const float4 b = ((const float4*)in)[id * 2 + 1];
    short8 o;
    o[0] = f2b(a.x); o[1] = f2b(a.y); o[2] = f2b(a.z); o[3] = f2b(a.w);
    o[4] = f2b(b.x); o[5] = f2b(b.y); o[6] = f2b(b.z); o[7] = f2b(b.w);
    ((short8*)out)[id] = o;
}

// ---------------------------------------------------------------------------
// All 6 weight transposes in ONE kernel. 64x64 fp32->bf16 tiles via LDS.
// ---------------------------------------------------------------------------
__device__ __forceinline__ void tr_tile(const float* __restrict__ W,
                                        bf16* __restrict__ WT,
                                        int K, int N, int k0, int n0,
                                        float (*tile)[65])
{
    const int ty = threadIdx.x >> 4, tx = threadIdx.x & 15;
    #pragma unroll
    for (int i = 0; i < 4; ++i) {
        const int k = ty + i * 16;
        const float4 v = *(const float4*)&W[(long)(k0 + k) * N + n0 + tx * 4];
        tile[k][tx * 4 + 0] = v.x; tile[k][tx * 4 + 1] = v.y;
        tile[k][tx * 4 + 2] = v.z; tile[k][tx * 4 + 3] = v.w;
    }
    __syncthreads();
    #pragma unroll
    for (int i = 0; i < 4; ++i) {
        const int n = ty + i * 16;
        bf16x4 o;
        #pragma unroll
        for (int j = 0; j < 4; ++j) o[j] = f2b(tile[tx * 4 + j][n]);
        *(bf16x4*)&WT[(long)(n0 + n) * K + k0 + tx * 4] = o;
    }
}

__global__ __launch_bounds__(256)
void k_transpose_all(const float* __restrict__ Wq, const float* __restrict__ Wk,
                     const float* __restrict__ Wv, const float* __restrict__ Wm,
                     const float* __restrict__ W1, const float* __restrict__ W2,
                     bf16* __restrict__ WqT, bf16* __restrict__ WkT,
                     bf16* __restrict__ WvT, bf16* __restrict__ WmT,
                     bf16* __restrict__ W1T, bf16* __restrict__ W2T)
{
    __shared__ float tile[64][65];
    const int b = blockIdx.x;
    const float* W; bf16* WT; int K, N, local;
    if      (b < 16)  { W = Wq; WT = WqT; K = 256; N = 256; local = b; }
    else if (b < 32)  { W = Wk; WT = WkT; K = 256; N = 256; local = b - 16; }
    else if (b < 48)  { W = Wv; WT = WvT; K = 256; N = 256; local = b - 32; }
    else if (b < 64)  { W = Wm; WT = WmT; K = 256; N = 256; local = b - 48; }
    else if (b < 128) { W = W1; WT = W1T; K = 512; N = 512; local = b - 64; }
    else              { W = W2; WT = W2T; K = 512; N = 256; local = b - 128; }
    const int tk = K / 64;
    const int k0 = (local % tk) * 64, n0 = (local / tk) * 64;
    tr_tile(W, WT, K, N, k0, n0, tile);
}

// ---------------------------------------------------------------------------
// GEMM: C[M,N] = A[M,K] @ W[K,N], W pre-transposed as BT[N,K] (bf16).
// 128x128 tile, BK=64, 4 waves, 16x16x32 MFMA.  EPI: 1 = elu+1 (bf16)
// ---------------------------------------------------------------------------
template<int EPI>
__global__ __launch_bounds__(256)
void k_gemm(const bf16* __restrict__ A, const bf16* __restrict__ BT,
            void* __restrict__ C, int M, int N, int K, float escale)
{
    __shared__ __attribute__((aligned(16))) bf16 Asm[128 * 64];
    __shared__ __attribute__((aligned(16))) bf16 Bsm[128 * 64];
    const int tid  = threadIdx.x;
    const int wave = tid >> 6, lane = tid & 63;
    const int wm = wave >> 1, wn = wave & 1;
    const long row0 = (long)blockIdx.x * 128;
    const long col0 = (long)blockIdx.y * 128;

    f32x4 acc[4][4] = {};
    const int lr = lane >> 3;
    const int lc = (lane & 7) * 8;

    for (int kt = 0; kt < K; kt += 64) {
        #pragma unroll
        for (int i = 0; i < 4; ++i) {
            const int grp = wave * 4 + i;
            const long r  = grp * 8 + lr;
            async16(A  + (row0 + r) * K + kt + lc, &Asm[grp * 512]);
            async16(BT + (col0 + r) * K + kt + lc, &Bsm[grp * 512]);
        }
        __syncthreads();
        #pragma unroll
        for (int ks = 0; ks < 2; ++ks) {
            short8 a[4], b[4];
            #pragma unroll
            for (int m = 0; m < 4; ++m)
                a[m] = *(const short8*)&Asm[(wm*64 + m*16 + (lane & 15))*64 + ks*32 + (lane>>4)*8];
            #pragma unroll
            for (int n = 0; n < 4; ++n)
                b[n] = *(const short8*)&Bsm[(wn*64 + n*16 + (lane & 15))*64 + ks*32 + (lane>>4)*8];
            #pragma unroll
            for (int m = 0; m < 4; ++m)
                #pragma unroll
                for (int n = 0; n < 4; ++n)
                    acc[m][n] = __builtin_amdgcn_mfma_f32_16x16x32_bf16(a[m], b[n], acc[m][n], 0, 0, 0);
        }
        __syncthreads();
    }

    #pragma unroll
    for (int m = 0; m < 4; ++m) {
        #pragma unroll
        for (int n = 0; n < 4; ++n) {
            #pragma unroll
            for (int r = 0; r < 4; ++r) {
                const long row = row0 + wm*64 + m*16 + (lane >> 4)*4 + r;
                const long col = col0 + wn*64 + n*16 + (lane & 15);
                float v = acc[m][n][r];
                if constexpr (EPI == 1) v = v > 0.f ? v + 1.f : __expf(v);
                if constexpr (EPI == 2) v *= escale;
                ((bf16*)C)[row * N + col] = __float2bfloat16(v);
            }
        }
    }
}

// ---------------------------------------------------------------------------
// Fused K+V projection: B = [WkT;WvT] contiguous [512][256].
// blockIdx.y 0-1: K half (elu+1 -> Kout); 2-3: V half (*escale -> Vout).
// ---------------------------------------------------------------------------
__global__ __launch_bounds__(256)
void k_gemmKV(const bf16* __restrict__ A, const bf16* __restrict__ BT,
              bf16* __restrict__ Kout, bf16* __restrict__ Vout, float escale)
{
    __shared__ __attribute__((aligned(16))) bf16 Asm[128 * 64];
    __shared__ __attribute__((aligned(16))) bf16 Bsm[128 * 64];
    const int tid  = threadIdx.x;
    const int wave = tid >> 6, lane = tid & 63;
    const int wm = wave >> 1, wn = wave & 1;
    const long row0 = (long)blockIdx.x * 128;
    const long col0 = (long)blockIdx.y * 128;      // 0..511 over [WkT;WvT]
    const bool isK  = blockIdx.y < 2;
    bf16* Cout = isK ? Kout : Vout;
    const long cofs = isK ? col0 : col0 - 256;

    f32x4 acc[4][4] = {};
    const int lr = lane >> 3;
    const int lc = (lane & 7) * 8;

    for (int kt = 0; kt < 256; kt += 64) {
        #pragma unroll
        for (int i = 0; i < 4; ++i) {
            const int grp = wave * 4 + i;
            const long r  = grp * 8 + lr;
            async16(A  + (row0 + r) * 256 + kt + lc, &Asm[grp * 512]);
            async16(BT + (col0 + r) * 256 + kt + lc, &Bsm[grp * 512]);
        }
        __syncthreads();
        #pragma unroll
        for (int ks = 0; ks < 2; ++ks) {
            short8 a[4], b[4];
            #pragma unroll
            for (int m = 0; m < 4; ++m)
                a[m] = *(const short8*)&Asm[(wm*64 + m*16 + (lane & 15))*64 + ks*32 + (lane>>4)*8];
            #pragma unroll
            for (int n = 0; n < 4; ++n)
                b[n] = *(const short8*)&Bsm[(wn*64 + n*16 + (lane & 15))*64 + ks*32 + (lane>>4)*8];
            #pragma unroll
            for (int m = 0; m < 4; ++m)
                #pragma unroll
                for (int n = 0; n < 4; ++n)
                    acc[m][n] = __builtin_amdgcn_mfma_f32_16x16x32_bf16(a[m], b[n], acc[m][n], 0, 0, 0);
        }
        __syncthreads();
    }

    #pragma unroll
    for (int m = 0; m < 4; ++m) {
        #pragma unroll
        for (int n = 0; n < 4; ++n) {
            #pragma unroll
            for (int r = 0; r < 4; ++r) {
                const long row = row0 + wm*64 + m*16 + (lane >> 4)*4 + r;
                const long col = cofs + wn*64 + n*16 + (lane & 15);
                float v = acc[m][n][r];
                if (isK) v = v > 0.f ? v + 1.f : __expf(v);
                else     v *= escale;
                Cout[row * 256 + col] = __float2bfloat16(v);
            }
        }
    }
}

// ---------------------------------------------------------------------------
// W1 GEMM, split-K A (virtual hcat = [A0|A1]): t = relu([A0|A1] @ W1)
// ---------------------------------------------------------------------------
__global__ __launch_bounds__(256)
void k_gemmW1(const bf16* __restrict__ A0, const bf16* __restrict__ A1,
              const bf16* __restrict__ BT, bf16* __restrict__ C)
{
    __shared__ __attribute__((aligned(16))) bf16 Asm[128 * 64];
    __shared__ __attribute__((aligned(16))) bf16 Bsm[128 * 64];
    const int tid  = threadIdx.x;
    const int wave = tid >> 6, lane = tid & 63;
    const int wm = wave >> 1, wn = wave & 1;
    const long row0 = (long)blockIdx.x * 128;
    const long col0 = (long)blockIdx.y * 128;

    f32x4 acc[4][4] = {};
    const int lr = lane >> 3;
    const int lc = (lane & 7) * 8;

    for (int kt = 0; kt < 512; kt += 64) {
        const bf16* Asrc = (kt < 256) ? A0 : A1;
        const int kk = kt & 255;
        #pragma unroll
        for (int i = 0; i < 4; ++i) {
            const int grp = wave * 4 + i;
            const long r  = grp * 8 + lr;
            async16(Asrc + (row0 + r) * 256 + kk + lc, &Asm[grp * 512]);
            async16(BT   + (col0 + r) * 512 + kt + lc, &Bsm[grp * 512]);
        }
        __syncthreads();
        #pragma unroll
        for (int ks = 0; ks < 2; ++ks) {
            short8 a[4], b[4];
            #pragma unroll
            for (int m = 0; m < 4; ++m)
                a[m] = *(const short8*)&Asm[(wm*64 + m*16 + (lane & 15))*64 + ks*32 + (lane>>4)*8];
            #pragma unroll
            for (int n = 0; n < 4; ++n)
                b[n] = *(const short8*)&Bsm[(wn*64 + n*16 + (lane & 15))*64 + ks*32 + (lane>>4)*8];
            #pragma unroll
            for (int m = 0; m < 4; ++m)
                #pragma unroll
                for (int n = 0; n < 4; ++n)
                    acc[m][n] = __builtin_amdgcn_mfma_f32_16x16x32_bf16(a[m], b[n], acc[m][n], 0, 0, 0);
        }
        __syncthreads();
    }

    #pragma unroll
    for (int m = 0; m < 4; ++m) {
        #pragma unroll
        for (int n = 0; n < 4; ++n) {
            #pragma unroll
            for (int r = 0; r < 4; ++r) {
                const long row = row0 + wm*64 + m*16 + (lane >> 4)*4 + r;
                const long col = col0 + wn*64 + n*16 + (lane & 15);
                const float v = acc[m][n][r];
                C[row * 512 + col] = __float2bfloat16(v > 0.f ? v : 0.f);
            }
        }
    }
}

// ---------------------------------------------------------------------------
// Fused GEMM + row-LayerNorm (N=256 = full tile width). 64x256 tile,
// 8 waves, 512 threads, grid M/64.
// RES=false: out = bf16 LN(A@B)       RES=true: out = fp32 x + LN(A@B)
// ---------------------------------------------------------------------------
template<int KK, bool RES>
__global__ __launch_bounds__(512)
void k_gemm_ln(const bf16* __restrict__ A, const bf16* __restrict__ BT,
               const float* __restrict__ g, const float* __restrict__ b,
               const float* __restrict__ xres, void* __restrict__ out)
{
    __shared__ __attribute__((aligned(16))) bf16 Asm[64 * 64];
    __shared__ __attribute__((aligned(16))) bf16 Bsm[256 * 64];
    __shared__ float lnS[4][64];
    __shared__ float lnQ[4][64];
    const int t = threadIdx.x, w = t >> 6, lane = t & 63;
    const int wm = w >> 2, wn = w & 3;
    const long row0 = (long)blockIdx.x * 64;
    const int lr = lane >> 3, lc = (lane & 7) * 8;
    const int lg = lane >> 4, l15 = lane & 15;

    f32x4 acc[2][4] = {};

    for (int kt = 0; kt < KK; kt += 64) {
        async16(A + (row0 + w * 8 + lr) * KK + kt + lc, &Asm[w * 512]);
        #pragma unroll
        for (int i = 0; i < 4; ++i) {
            const int ch = i * 8 + w;
            async16(BT + (long)(ch * 8 + lr) * KK + kt + lc, &Bsm[ch * 512]);
        }
        __syncthreads();
        #pragma unroll
        for (int ks = 0; ks < 2; ++ks) {
            short8 a[2], bb[4];
            #pragma unroll
            for (int m = 0; m < 2; ++m)
                a[m] = *(const short8*)&Asm[(wm*32 + m*16 + l15)*64 + ks*32 + lg*8];
            #pragma unroll
            for (int n = 0; n < 4; ++n)
                bb[n] = *(const short8*)&Bsm[(wn*64 + n*16 + l15)*64 + ks*32 + lg*8];
            #pragma unroll
            for (int m = 0; m < 2; ++m)
                #pragma unroll
                for (int n = 0; n < 4; ++n)
                    acc[m][n] = __builtin_amdgcn_mfma_f32_16x16x32_bf16(a[m], bb[n], acc[m][n], 0, 0, 0);
        }
        __syncthreads();
    }

    #pragma unroll
    for (int m = 0; m < 2; ++m) {
        #pragma unroll
        for (int r = 0; r < 4; ++r) {
            float ls = 0.f, lq = 0.f;
            #pragma unroll
            for (int n = 0; n < 4; ++n) {
                const float v = acc[m][n][r];
                ls += v; lq += v * v;
            }
            #pragma unroll
            for (int o = 1; o < 16; o <<= 1) {
                ls += __shfl_xor(ls, o);
                lq += __shfl_xor(lq, o);
            }
            if (l15 == 0) {
                const int row = wm * 32 + m * 16 + lg * 4 + r;
                lnS[wn][row] = ls;
                lnQ[wn][row] = lq;
            }
        }
    }
    __syncthreads();

    float gv[4], bv[4];
    #pragma unroll
    for (int n = 0; n < 4; ++n) {
        const int col = wn * 64 + n * 16 + l15;
        gv[n] = g[col]; bv[n] = b[col];
    }
    #pragma unroll
    for (int m = 0; m < 2; ++m) {
        #pragma unroll
        for (int r = 0; r < 4; ++r) {
            const int row = wm * 32 + m * 16 + lg * 4 + r;
            const float S  = lnS[0][row] + lnS[1][row] + lnS[2][row] + lnS[3][row];
            const float Qq = lnQ[0][row] + lnQ[1][row] + lnQ[2][row] + lnQ[3][row];
            const float mean = S * (1.f / 256.f);
            const float var  = Qq * (1.f / 256.f) - mean * mean;
            const float rstd = rsqrtf(var + EPS_LN);
            const long grow = row0 + row;
            #pragma unroll
            for (int n = 0; n < 4; ++n) {
                const int col = wn * 64 + n * 16 + l15;
                const float y = (acc[m][n][r] - mean) * rstd * gv[n] + bv[n];
                if constexpr (RES)
                    ((float*)out)[grow * 256 + col] = xres[grow * 256 + col] + y;
                else
                    ((bf16*)out)[grow * 256 + col] = __float2bfloat16(y);
            }
        }
    }
}

// ---------------------------------------------------------------------------
// Partial KV / Ksum. Grid (128 s-chunks, 4 batches), 64 rows per block.
// ---------------------------------------------------------------------------
__global__ __launch_bounds__(256)
void k_kv2(const bf16* __restrict__ Kb, const bf16* __restrict__ Vb,
           bf16* __restrict__ partKV, float* __restrict__ partKs)
{
    __shared__ __attribute__((aligned(16))) bf16 Kls[16 * 256];
    __shared__ __attribute__((aligned(16))) bf16 Vls[16 * 256];
    const int c = blockIdx.x;
    const int n = blockIdx.y;
    const int t = threadIdx.x;
    const int w = t >> 6, lane = t & 63;
    const int h = t >> 5, tt = t & 31, dg = tt >> 2, vg = tt & 3;
    float acc[4][8] = {};
    float ksacc[4] = {};
    const long base = ((long)n * 8192 + (long)c * 64) * 256;

    for (int s0 = 0; s0 < 64; s0 += 16) {
        #pragma unroll
        for (int p = 0; p < 2; ++p) {
            const int ch = p * 4 + w;
            async16(Kb + base + s0 * 256 + ch * 512 + lane * 8, &Kls[ch * 512]);
            async16(Vb + base + s0 * 256 + ch * 512 + lane * 8, &Vls[ch * 512]);
        }
        __syncthreads();
        #pragma unroll
        for (int i = 0; i < 16; ++i) {
            const bf16x4 kk = *(const bf16x4*)&Kls[i * 256 + h * 32 + dg * 4];
            const short8 vv = *(const short8*)&Vls[i * 256 + h * 32 + vg * 8];
            float kf[4], vf[8];
            #pragma unroll
            for (int j = 0; j < 4; ++j) { kf[j] = b2f(kk[j]); ksacc[j] += kf[j]; }
            #pragma unroll
            for (int u = 0; u < 8; ++u) vf[u] = b2f(vv[u]);
            #pragma unroll
            for (int j = 0; j < 4; ++j)
                #pragma unroll
                for (int u = 0; u < 8; ++u) acc[j][u] += kf[j] * vf[u];
        }
        __syncthreads();
    }

    const long pb = (long)(c * 4 + n) * 8192 + h * 1024;
    #pragma unroll
    for (int j = 0; j < 4; ++j) {
        short8 o;
        #pragma unroll
        for (int u = 0; u < 8; ++u) o[u] = f2b(acc[j][u]);
        *(short8*)&partKV[pb + (dg * 4 + j) * 32 + vg * 8] = o;
    }
    if (vg == 0) {
        f32x4 o4;
        #pragma unroll
        for (int j = 0; j < 4; ++j) o4[j] = ksacc[j];
        *(f32x4*)&partKs[(c * 4 + n) * 256 + h * 32 + dg * 4] = o4;
    }
}

// ---------------------------------------------------------------------------
// KV reduce stage 1: 128 -> 8 partials. Grid 256 = (n<<6)|(h<<3)|c8.
// ---------------------------------------------------------------------------
__global__ __launch_bounds__(256)
void k_kvred1(const bf16* __restrict__ partKV, const float* __restrict__ partKs,
              bf16* __restrict__ part2, float* __restrict__ part2Ks)
{
    const int bid = blockIdx.x;
    const int c8 = bid & 7, h = (bid >> 3) & 7, n = bid >> 6;
    const int t = threadIdx.x;
    const int d = t >> 3, vg = t & 7;
    float s[4] = {};
    #pragma unroll
    for (int i = 0; i < 16; ++i) {
        const int c = c8 * 16 + i;
        const bf16x4 p = *(const bf16x4*)&partKV[(long)(c * 4 + n) * 8192 + h * 1024 + d * 32 + vg * 4];
        #pragma unroll
        for (int j = 0; j < 4; ++j) s[j] += b2f(p[j]);
    }
    bf16x4 o;
    #pragma unroll
    for (int j = 0; j < 4; ++j) o[j] = f2b(s[j]);
    *(bf16x4*)&part2[(long)(c8 * 4 + n) * 8192 + h * 1024 + d * 32 + vg * 4] = o;
    if (vg == 0) {
        float ks = 0.f;
        #pragma unroll
        for (int i = 0; i < 16; ++i) {
            const int c = c8 * 16 + i;
            ks += partKs[(c * 4 + n) * 256 + h * 32 + d];
        }
        part2Ks[(c8 * 4 + n) * 256 + h * 32 + d] = ks;
    }
}

// ---------------------------------------------------------------------------
// KV reduce stage 2: 8 partials -> KVaug bf16 [n][h][32][48] (col 32 = Ksum)
// ---------------------------------------------------------------------------
__global__ __launch_bounds__(256)
void k_kvred2(const bf16* __restrict__ part2, const float* __restrict__ part2Ks,
              bf16* __restrict__ KVb)
{
    const int b = blockIdx.x;
    const int n = b >> 3, h = b & 7;
    const int t = threadIdx.x;
    const int d = t >> 3, vg = t & 7;
    float s[4] = {};
    #pragma unroll
    for (int c8 = 0; c8 < 8; ++c8) {
        const bf16x4 p = *(const bf16x4*)&part2[(long)(c8 * 4 + n) * 8192 + h * 1024 + d * 32 + vg * 4];
        #pragma unroll
        for (int j = 0; j < 4; ++j) s[j] += b2f(p[j]);
    }
    bf16* dst = KVb + ((long)n * 8 + h) * 1536 + d * 48;
    bf16x4 o;
    #pragma unroll
    for (int j = 0; j < 4; ++j) o[j] = f2b(s[j]);
    *(bf16x4*)&dst[vg * 4] = o;
    if (vg == 0) {
        float ks = 0.f;
        #pragma unroll
        for (int c8 = 0; c8 < 8; ++c8) ks += part2Ks[(c8 * 4 + n) * 256 + h * 32 + d];
        short8 z0 = {};
        z0[0] = f2b(ks);
        *(short8*)&dst[32] = z0;
        short8 zz = {};
        *(short8*)&dst[40] = zz;
    }
}

// ---------------------------------------------------------------------------
// MFMA attention: per (n,h): Q[L,32] @ KVaug[32][48]; col 32 = Ksum -> z.
// ---------------------------------------------------------------------------
__global__ __launch_bounds__(256)
void k_attn2(const bf16* __restrict__ Qb, const bf16* __restrict__ KVb,
             bf16* __restrict__ msg1)
{
    __shared__ __attribute__((aligned(16))) bf16 kvls[12288];
    const int n = blockIdx.y;
    const long row0 = (long)n * 8192 + (long)blockIdx.x * 128;
    const int t = threadIdx.x, w = t >> 6, lane = t & 63;
    const int lr = lane & 15, lg = lane >> 4;

    #pragma unroll
    for (int p = 0; p < 6; ++p) {
        const int ch = p * 4 + w;
        async16(KVb + (long)n * 12288 + ch * 512 + lane * 8, &kvls[ch * 512]);
    }
    __syncthreads();

    for (int h = 0; h < 8; ++h) {
        short8 b0, b1, bz;
        #pragma unroll
        for (int j = 0; j < 8; ++j) {
            const int drow = h * 1536 + (lg * 8 + j) * 48;
            b0[j] = __builtin_bit_cast(short, kvls[drow + lr]);
            b1[j] = __builtin_bit_cast(short, kvls[drow + 16 + lr]);
            bz[j] = __builtin_bit_cast(short, kvls[drow + 32 + lr]);
        }
        #pragma unroll
        for (int m = 0; m < 2; ++m) {
            const long rbase = row0 + w * 32 + m * 16;
            const short8 a = *(const short8*)&Qb[(rbase + lr) * 256 + h * 32 + lg * 8];
            f32x4 a0 = {}, a1 = {}, az = {};
            a0 = __builtin_amdgcn_mfma_f32_16x16x32_bf16(a, b0, a0, 0, 0, 0);
            a1 = __builtin_amdgcn_mfma_f32_16x16x32_bf16(a, b1, a1, 0, 0, 0);
            az = __builtin_amdgcn_mfma_f32_16x16x32_bf16(a, bz, az, 0, 0, 0);
            #pragma unroll
            for (int r = 0; r < 4; ++r) {
                const float z   = __shfl(az[r], lane & 48);
                const float inv = 8192.f / (z + EPS_ATTN);
                const long row = rbase + lg * 4 + r;
                bf16* o = msg1 + row * 256 + h * 32;
                o[lr]      = __float2bfloat16(a0[r] * inv);
                o[16 + lr] = __float2bfloat16(a1[r] * inv);
            }
        }
    }
}

// ---------------------------------------------------------------------------
extern "C" void kernel_launch(void* const* d_in, const int* in_sizes, int n_in,
                              void* d_out, int out_size, void* d_ws, size_t ws_size,
                              hipStream_t stream)
{
    const float* x      = (const float*)d_in[0];
    const float* source = (const float*)d_in[1];
    const float* Wq     = (const float*)d_in[2];
    const float* Wk     = (const float*)d_in[3];
    const float* Wv     = (const float*)d_in[4];
    const float* Wm     = (const float*)d_in[5];
    const float* W1     = (const float*)d_in[6];
    const float* W2     = (const float*)d_in[7];
    const float* g1     = (const float*)d_in[8];
    const float* b1     = (const float*)d_in[9];
    const float* g2     = (const float*)d_in[10];
    const float* b2     = (const float*)d_in[11];
    float* out = (float*)d_out;

    const long M = 32768;
    const size_t U = 32768ull * 256ull;
    char* w = (char*)d_ws;

    // slots (16 MB each); lifetimes:
    bf16* x_bf  = (bf16*)(w + 0 * U * 2);   // alive through W1 gemm
    bf16* s_bf  = (bf16*)(w + 1 * U * 2);   // dead after KV gemm
    bf16* Q_bf  = (bf16*)(w + 2 * U * 2);   // dead after attn
    bf16* K_bf  = (bf16*)(w + 3 * U * 2);   // dead after k_kv2
    bf16* V_bf  = (bf16*)(w + 4 * U * 2);   // dead after k_kv2
    bf16* msg1  = (bf16*)(w + 5 * U * 2);   // dead after merge gemm
    bf16* msgln = (bf16*)(w + 1 * U * 2);   // reuse slot 1
    bf16* t_bf  = (bf16*)(w + 3 * U * 2);   // slots 3-4 ([32768,512])

    char* wx = w + 7 * U * 2;
    bf16* WqT = (bf16*)wx; wx += 65536 * 2;
    bf16* WkT = (bf16*)wx; wx += 65536 * 2;   // contiguous with WvT -> [512][256]
    bf16* WvT = (bf16*)wx; wx += 65536 * 2;
    bf16* WmT = (bf16*)wx; wx += 65536 * 2;
    bf16* W1T = (bf16*)wx; wx += 262144 * 2;
    bf16* W2T = (bf16*)wx; wx += 131072 * 2;
    bf16* partKV = (bf16*)wx; wx += 4194304 * 2;   // 128 x 4 x 8192
    float* partKs = (float*)wx; wx += 131072 * 4;  // 128 x 4 x 256
    bf16* part2  = (bf16*)wx; wx += 262144 * 2;    // 8 x 4 x 8192
    float* part2Ks = (float*)wx; wx += 8192 * 4;   // 8 x 4 x 256
    bf16* KVb    = (bf16*)wx; wx += 49152 * 2;     // [n][h][32][48]

    const dim3 blk(256);

    // 1) converts + weight transposes
    k_cvt8x2<<<dim3(4096, 2), blk, 0, stream>>>(x, source, x_bf, s_bf, M * 256 / 8);
    k_transpose_all<<<160, blk, 0, stream>>>(Wq, Wk, Wv, Wm, W1, W2,
                                             WqT, WkT, WvT, WmT, W1T, W2T);

    // 2) projections: Q (elu+1), fused K+V
    k_gemm<1><<<dim3(256, 2), blk, 0, stream>>>(x_bf, WqT, Q_bf, 32768, 256, 256, 0.f);
    k_gemmKV<<<dim3(256, 4), blk, 0, stream>>>(s_bf, WkT, K_bf, V_bf, 1.f / 8192.f);

    // 3) KV + Ksum -> KVaug (2-stage deterministic reduce)
    k_kv2<<<dim3(128, 4), blk, 0, stream>>>(K_bf, V_bf, partKV, partKs);
    k_kvred1<<<256, blk, 0, stream>>>(partKV, partKs, part2, part2Ks);
    k_kvred2<<<32, blk, 0, stream>>>(part2, part2Ks, KVb);

    // 4) MFMA attention -> msg1
    k_attn2<<<dim3(64, 4), blk, 0, stream>>>(Q_bf, KVb, msg1);

    // 5) merge GEMM + LN1 fused -> msgln (bf16)
    k_gemm_ln<256, false><<<512, dim3(512), 0, stream>>>(msg1, WmT, g1, b1, nullptr, msgln);

    // 6) MLP split: t = relu([x_bf|msgln]@W1); out = x + LN2(t@W2)
    k_gemmW1<<<dim3(256, 4), blk, 0, stream>>>(x_bf, msgln, W1T, t_bf);
    k_gemm_ln<512, true><<<512, dim3(512), 0, stream>>>(t_bf, W2T, g2, b2, x, out);
}

// Round 8
// 149.604 us; speedup vs baseline: 1.8070x; 1.0882x over previous
//
#include <hip/hip_runtime.h>
#include <hip/hip_bf16.h>
#include <stdint.h>

typedef __hip_bfloat16 bf16;
typedef __attribute__((ext_vector_type(8))) short short8;
typedef __attribute__((ext_vector_type(4))) short bf16x4;
typedef __attribute__((ext_vector_type(4))) float f32x4;

#define EPS_ATTN 1e-6f
#define EPS_LN   1e-5f

__device__ __forceinline__ float b2f(short s) {
    return __builtin_bit_cast(float, (unsigned)((unsigned short)s) << 16);
}
__device__ __forceinline__ short f2b(float f) {
    return __builtin_bit_cast(short, __float2bfloat16(f));
}

// ---------------------------------------------------------------------------
// async global->LDS, 16B per lane. LDS dest = wave-uniform base + lane*16.
// ---------------------------------------------------------------------------
__device__ __forceinline__ void async16(const void* g, void* l) {
    __builtin_amdgcn_global_load_lds(
        (const __attribute__((address_space(1))) void*)g,
        (__attribute__((address_space(3))) void*)l,
        16, 0, 0);
}

// ---------------------------------------------------------------------------
// Prep: fp32->bf16 converts (x, source) + all 6 weight transposes, ONE launch.
// blocks 0-4095 cvt x | 4096-8191 cvt source | 8192-8351 transposes
// ---------------------------------------------------------------------------
__global__ __launch_bounds__(256)
void k_prep(const float* __restrict__ x, const float* __restrict__ src,
            bf16* __restrict__ x_bf, bf16* __restrict__ s_bf,
            const float* __restrict__ Wq, const float* __restrict__ Wk,
            const float* __restrict__ Wv, const float* __restrict__ Wm,
            const float* __restrict__ W1, const float* __restrict__ W2,
            bf16* __restrict__ WqT, bf16* __restrict__ WkT,
            bf16* __restrict__ WvT, bf16* __restrict__ WmT,
            bf16* __restrict__ W1T, bf16* __restrict__ W2T)
{
    __shared__ float tile[64][65];
    const int blk = blockIdx.x;
    if (blk < 8192) {
        const float* in = (blk < 4096) ? x : src;
        bf16* out       = (blk < 4096) ? x_bf : s_bf;
        const long id = (long)(blk & 4095) * 256 + threadIdx.x;
        const float4 a = ((const float4*)in)[id * 2];
        const float4 b = ((const float4*)in)[id * 2 + 1];
        short8 o;
        o[0] = f2b(a.x); o[1] = f2b(a.y); o[2] = f2b(a.z); o[3] = f2b(a.w);
        o[4] = f2b(b.x); o[5] = f2b(b.y); o[6] = f2b(b.z); o[7] = f2b(b.w);
        ((short8*)out)[id] = o;
        return;
    }
    const int b = blk - 8192;
    const float* W; bf16* WT; int K, N, local;
    if      (b < 16)  { W = Wq; WT = WqT; K = 256; N = 256; local = b; }
    else if (b < 32)  { W = Wk; WT = WkT; K = 256; N = 256; local = b - 16; }
    else if (b < 48)  { W = Wv; WT = WvT; K = 256; N = 256; local = b - 32; }
    else if (b < 64)  { W = Wm; WT = WmT; K = 256; N = 256; local = b - 48; }
    else if (b < 128) { W = W1; WT = W1T; K = 512; N = 512; local = b - 64; }
    else              { W = W2; WT = W2T; K = 512; N = 256; local = b - 128; }
    const int tk = K / 64;
    const int k0 = (local % tk) * 64, n0 = (local / tk) * 64;
    const int ty = threadIdx.x >> 4, tx = threadIdx.x & 15;
    #pragma unroll
    for (int i = 0; i < 4; ++i) {
        const int k = ty + i * 16;
        const float4 v = *(const float4*)&W[(long)(k0 + k) * N + n0 + tx * 4];
        tile[k][tx * 4 + 0] = v.x; tile[k][tx * 4 + 1] = v.y;
        tile[k][tx * 4 + 2] = v.z; tile[k][tx * 4 + 3] = v.w;
    }
    __syncthreads();
    #pragma unroll
    for (int i = 0; i < 4; ++i) {
        const int n = ty + i * 16;
        bf16x4 o;
        #pragma unroll
        for (int j = 0; j < 4; ++j) o[j] = f2b(tile[tx * 4 + j][n]);
        *(bf16x4*)&WT[(long)(n0 + n) * K + k0 + tx * 4] = o;
    }
}

// ---------------------------------------------------------------------------
// Fused K+V projection, XCD-swizzled. B = [WkT;WvT] contiguous [512][256].
// ---------------------------------------------------------------------------
__global__ __launch_bounds__(256)
void k_gemmKV(const bf16* __restrict__ A, const bf16* __restrict__ BT,
              bf16* __restrict__ Kout, bf16* __restrict__ Vout, float escale)
{
    __shared__ __attribute__((aligned(16))) bf16 Asm[128 * 64];
    __shared__ __attribute__((aligned(16))) bf16 Bsm[128 * 64];
    const int tid  = threadIdx.x;
    const int wave = tid >> 6, lane = tid & 63;
    const int wm = wave >> 1, wn = wave & 1;
    const int flat = blockIdx.y * gridDim.x + blockIdx.x;          // 0..1023
    const int swz  = (flat & 7) * 128 + (flat >> 3);               // bijective
    const long row0 = (long)(swz >> 2) * 128;
    const int  cy   = swz & 3;
    const long col0 = (long)cy * 128;
    const bool isK  = cy < 2;
    bf16* Cout = isK ? Kout : Vout;
    const long cofs = isK ? col0 : col0 - 256;

    f32x4 acc[4][4] = {};
    const int lr = lane >> 3;
    const int lc = (lane & 7) * 8;

    for (int kt = 0; kt < 256; kt += 64) {
        #pragma unroll
        for (int i = 0; i < 4; ++i) {
            const int grp = wave * 4 + i;
            const long r  = grp * 8 + lr;
            async16(A  + (row0 + r) * 256 + kt + lc, &Asm[grp * 512]);
            async16(BT + (col0 + r) * 256 + kt + lc, &Bsm[grp * 512]);
        }
        __syncthreads();
        #pragma unroll
        for (int ks = 0; ks < 2; ++ks) {
            short8 a[4], b[4];
            #pragma unroll
            for (int m = 0; m < 4; ++m)
                a[m] = *(const short8*)&Asm[(wm*64 + m*16 + (lane & 15))*64 + ks*32 + (lane>>4)*8];
            #pragma unroll
            for (int n = 0; n < 4; ++n)
                b[n] = *(const short8*)&Bsm[(wn*64 + n*16 + (lane & 15))*64 + ks*32 + (lane>>4)*8];
            #pragma unroll
            for (int m = 0; m < 4; ++m)
                #pragma unroll
                for (int n = 0; n < 4; ++n)
                    acc[m][n] = __builtin_amdgcn_mfma_f32_16x16x32_bf16(a[m], b[n], acc[m][n], 0, 0, 0);
        }
        __syncthreads();
    }

    #pragma unroll
    for (int m = 0; m < 4; ++m) {
        #pragma unroll
        for (int n = 0; n < 4; ++n) {
            #pragma unroll
            for (int r = 0; r < 4; ++r) {
                const long row = row0 + wm*64 + m*16 + (lane >> 4)*4 + r;
                const long col = cofs + wn*64 + n*16 + (lane & 15);
                float v = acc[m][n][r];
                if (isK) v = v > 0.f ? v + 1.f : __expf(v);
                else     v *= escale;
                Cout[row * 256 + col] = __float2bfloat16(v);
            }
        }
    }
}

// ---------------------------------------------------------------------------
// W1 GEMM, split-K A (virtual hcat = [A0|A1]), XCD-swizzled.
// ---------------------------------------------------------------------------
__global__ __launch_bounds__(256)
void k_gemmW1(const bf16* __restrict__ A0, const bf16* __restrict__ A1,
              const bf16* __restrict__ BT, bf16* __restrict__ C)
{
    __shared__ __attribute__((aligned(16))) bf16 Asm[128 * 64];
    __shared__ __attribute__((aligned(16))) bf16 Bsm[128 * 64];
    const int tid  = threadIdx.x;
    const int wave = tid >> 6, lane = tid & 63;
    const int wm = wave >> 1, wn = wave & 1;
    const int flat = blockIdx.y * gridDim.x + blockIdx.x;          // 0..1023
    const int swz  = (flat & 7) * 128 + (flat >> 3);
    const long row0 = (long)(swz >> 2) * 128;
    const long col0 = (long)(swz & 3) * 128;

    f32x4 acc[4][4] = {};
    const int lr = lane >> 3;
    const int lc = (lane & 7) * 8;

    for (int kt = 0; kt < 512; kt += 64) {
        const bf16* Asrc = (kt < 256) ? A0 : A1;
        const int kk = kt & 255;
        #pragma unroll
        for (int i = 0; i < 4; ++i) {
            const int grp = wave * 4 + i;
            const long r  = grp * 8 + lr;
            async16(Asrc + (row0 + r) * 256 + kk + lc, &Asm[grp * 512]);
            async16(BT   + (col0 + r) * 512 + kt + lc, &Bsm[grp * 512]);
        }
        __syncthreads();
        #pragma unroll
        for (int ks = 0; ks < 2; ++ks) {
            short8 a[4], b[4];
            #pragma unroll
            for (int m = 0; m < 4; ++m)
                a[m] = *(const short8*)&Asm[(wm*64 + m*16 + (lane & 15))*64 + ks*32 + (lane>>4)*8];
            #pragma unroll
            for (int n = 0; n < 4; ++n)
                b[n] = *(const short8*)&Bsm[(wn*64 + n*16 + (lane & 15))*64 + ks*32 + (lane>>4)*8];
            #pragma unroll
            for (int m = 0; m < 4; ++m)
                #pragma unroll
                for (int n = 0; n < 4; ++n)
                    acc[m][n] = __builtin_amdgcn_mfma_f32_16x16x32_bf16(a[m], b[n], acc[m][n], 0, 0, 0);
        }
        __syncthreads();
    }

    #pragma unroll
    for (int m = 0; m < 4; ++m) {
        #pragma unroll
        for (int n = 0; n < 4; ++n) {
            #pragma unroll
            for (int r = 0; r < 4; ++r) {
                const long row = row0 + wm*64 + m*16 + (lane >> 4)*4 + r;
                const long col = col0 + wn*64 + n*16 + (lane & 15);
                const float v = acc[m][n][r];
                C[row * 512 + col] = __float2bfloat16(v > 0.f ? v : 0.f);
            }
        }
    }
}

// ---------------------------------------------------------------------------
// Fused GEMM(K=512) + LN2 + residual: out = fp32 x + LN(A@B). 64x256 tile,
// 8 waves, 512 threads, grid M/64.
// ---------------------------------------------------------------------------
__global__ __launch_bounds__(512)
void k_gemm_ln2(const bf16* __restrict__ A, const bf16* __restrict__ BT,
                const float* __restrict__ g, const float* __restrict__ b,
                const float* __restrict__ xres, float* __restrict__ out)
{
    __shared__ __attribute__((aligned(16))) bf16 Asm[64 * 64];
    __shared__ __attribute__((aligned(16))) bf16 Bsm[256 * 64];
    __shared__ float lnS[4][64];
    __shared__ float lnQ[4][64];
    const int t = threadIdx.x, w = t >> 6, lane = t & 63;
    const int wm = w >> 2, wn = w & 3;
    const long row0 = (long)blockIdx.x * 64;
    const int lr = lane >> 3, lc = (lane & 7) * 8;
    const int lg = lane >> 4, l15 = lane & 15;

    f32x4 acc[2][4] = {};

    for (int kt = 0; kt < 512; kt += 64) {
        async16(A + (row0 + w * 8 + lr) * 512 + kt + lc, &Asm[w * 512]);
        #pragma unroll
        for (int i = 0; i < 4; ++i) {
            const int ch = i * 8 + w;
            async16(BT + (long)(ch * 8 + lr) * 512 + kt + lc, &Bsm[ch * 512]);
        }
        __syncthreads();
        #pragma unroll
        for (int ks = 0; ks < 2; ++ks) {
            short8 a[2], bb[4];
            #pragma unroll
            for (int m = 0; m < 2; ++m)
                a[m] = *(const short8*)&Asm[(wm*32 + m*16 + l15)*64 + ks*32 + lg*8];
            #pragma unroll
            for (int n = 0; n < 4; ++n)
                bb[n] = *(const short8*)&Bsm[(wn*64 + n*16 + l15)*64 + ks*32 + lg*8];
            #pragma unroll
            for (int m = 0; m < 2; ++m)
                #pragma unroll
                for (int n = 0; n < 4; ++n)
                    acc[m][n] = __builtin_amdgcn_mfma_f32_16x16x32_bf16(a[m], bb[n], acc[m][n], 0, 0, 0);
        }
        __syncthreads();
    }

    #pragma unroll
    for (int m = 0; m < 2; ++m) {
        #pragma unroll
        for (int r = 0; r < 4; ++r) {
            float ls = 0.f, lq = 0.f;
            #pragma unroll
            for (int n = 0; n < 4; ++n) {
                const float v = acc[m][n][r];
                ls += v; lq += v * v;
            }
            #pragma unroll
            for (int o = 1; o < 16; o <<= 1) {
                ls += __shfl_xor(ls, o);
                lq += __shfl_xor(lq, o);
            }
            if (l15 == 0) {
                const int row = wm * 32 + m * 16 + lg * 4 + r;
                lnS[wn][row] = ls;
                lnQ[wn][row] = lq;
            }
        }
    }
    __syncthreads();

    float gv[4], bv[4];
    #pragma unroll
    for (int n = 0; n < 4; ++n) {
        const int col = wn * 64 + n * 16 + l15;
        gv[n] = g[col]; bv[n] = b[col];
    }
    #pragma unroll
    for (int m = 0; m < 2; ++m) {
        #pragma unroll
        for (int r = 0; r < 4; ++r) {
            const int row = wm * 32 + m * 16 + lg * 4 + r;
            const float S  = lnS[0][row] + lnS[1][row] + lnS[2][row] + lnS[3][row];
            const float Qq = lnQ[0][row] + lnQ[1][row] + lnQ[2][row] + lnQ[3][row];
            const float mean = S * (1.f / 256.f);
            const float var  = Qq * (1.f / 256.f) - mean * mean;
            const float rstd = rsqrtf(var + EPS_LN);
            const long grow = row0 + row;
            #pragma unroll
            for (int n = 0; n < 4; ++n) {
                const int col = wn * 64 + n * 16 + l15;
                const float y = (acc[m][n][r] - mean) * rstd * gv[n] + bv[n];
                out[grow * 256 + col] = xres[grow * 256 + col] + y;
            }
        }
    }
}

// ---------------------------------------------------------------------------
// MEGA: Q-proj + feature-map + attention + merge-GEMM + LN1 in one kernel.
// Block = 64 rows, 512 thr, 8 waves. msgln = LN1( attn(fmap(x@Wq)) @ Wm ).
// QM LDS buffer [64][264] holds Q then msg. KVaug read from global (L2).
// NOTE: fragment row/col index is l15 (lane&15); lr (lane>>3) is ONLY for
// staging — R7's bug was using lr in the attention phase.
// ---------------------------------------------------------------------------
__global__ __launch_bounds__(512)
void k_qaml(const bf16* __restrict__ xb, const bf16* __restrict__ WqT,
            const bf16* __restrict__ WmT, const bf16* __restrict__ KVb,
            const float* __restrict__ g, const float* __restrict__ b,
            bf16* __restrict__ msgln)
{
    __shared__ __attribute__((aligned(16))) bf16 Asm[64 * 64];
    __shared__ __attribute__((aligned(16))) bf16 Bsm[256 * 64];
    __shared__ __attribute__((aligned(16))) bf16 QM[64 * 264];
    __shared__ float lnS[4][64];
    __shared__ float lnQ[4][64];
    const int t = threadIdx.x, w = t >> 6, lane = t & 63;
    const int wm = w >> 2, wn = w & 3;
    const long row0 = (long)blockIdx.x * 64;
    const int n_b = (int)(row0 >> 13);             // batch index
    const int lr = lane >> 3, lc = (lane & 7) * 8;
    const int lg = lane >> 4, l15 = lane & 15;

    // ================= GEMM1: Q = fmap(x @ Wq) =================
    {
        f32x4 acc[2][4] = {};
        for (int kt = 0; kt < 256; kt += 64) {
            async16(xb + (row0 + w * 8 + lr) * 256 + kt + lc, &Asm[w * 512]);
            #pragma unroll
            for (int i = 0; i < 4; ++i) {
                const int ch = i * 8 + w;
                async16(WqT + (long)(ch * 8 + lr) * 256 + kt + lc, &Bsm[ch * 512]);
            }
            __syncthreads();
            #pragma unroll
            for (int ks = 0; ks < 2; ++ks) {
                short8 a[2], bb[4];
                #pragma unroll
                for (int m = 0; m < 2; ++m)
                    a[m] = *(const short8*)&Asm[(wm*32 + m*16 + l15)*64 + ks*32 + lg*8];
                #pragma unroll
                for (int n = 0; n < 4; ++n)
                    bb[n] = *(const short8*)&Bsm[(wn*64 + n*16 + l15)*64 + ks*32 + lg*8];
                #pragma unroll
                for (int m = 0; m < 2; ++m)
                    #pragma unroll
                    for (int n = 0; n < 4; ++n)
                        acc[m][n] = __builtin_amdgcn_mfma_f32_16x16x32_bf16(a[m], bb[n], acc[m][n], 0, 0, 0);
            }
            __syncthreads();
        }
        // fmap + write Q into QM
        #pragma unroll
        for (int m = 0; m < 2; ++m) {
            #pragma unroll
            for (int n = 0; n < 4; ++n) {
                #pragma unroll
                for (int r = 0; r < 4; ++r) {
                    const int row = wm * 32 + m * 16 + lg * 4 + r;
                    const int col = wn * 64 + n * 16 + l15;
                    float v = acc[m][n][r];
                    v = v > 0.f ? v + 1.f : __expf(v);
                    QM[row * 264 + col] = __float2bfloat16(v);
                }
            }
        }
    }
    __syncthreads();

    // ================= attention: wave w = head w ================
    {
        const bf16* kvh = KVb + (long)n_b * 12288 + w * 1536;
        short8 b0, b1, bz;
        #pragma unroll
        for (int j = 0; j < 8; ++j) {
            const int drow = (lg * 8 + j) * 48;
            b0[j] = __builtin_bit_cast(short, kvh[drow + l15]);
            b1[j] = __builtin_bit_cast(short, kvh[drow + 16 + l15]);
            bz[j] = __builtin_bit_cast(short, kvh[drow + 32 + l15]);
        }
        f32x4 ra0[4], ra1[4];
        #pragma unroll
        for (int m2 = 0; m2 < 4; ++m2) {
            const short8 a = *(const short8*)&QM[(m2 * 16 + l15) * 264 + w * 32 + lg * 8];
            f32x4 a0 = {}, a1 = {}, az = {};
            a0 = __builtin_amdgcn_mfma_f32_16x16x32_bf16(a, b0, a0, 0, 0, 0);
            a1 = __builtin_amdgcn_mfma_f32_16x16x32_bf16(a, b1, a1, 0, 0, 0);
            az = __builtin_amdgcn_mfma_f32_16x16x32_bf16(a, bz, az, 0, 0, 0);
            #pragma unroll
            for (int r = 0; r < 4; ++r) {
                const float z   = __shfl(az[r], lane & 48);
                const float inv = 8192.f / (z + EPS_ATTN);
                ra0[m2][r] = a0[r] * inv;
                ra1[m2][r] = a1[r] * inv;
            }
        }
        __syncthreads();   // all QM (Q) reads done, safe to overwrite
        #pragma unroll
        for (int m2 = 0; m2 < 4; ++m2) {
            #pragma unroll
            for (int r = 0; r < 4; ++r) {
                const int row = m2 * 16 + lg * 4 + r;
                QM[row * 264 + w * 32 + l15]      = __float2bfloat16(ra0[m2][r]);
                QM[row * 264 + w * 32 + 16 + l15] = __float2bfloat16(ra1[m2][r]);
            }
        }
    }
    __syncthreads();

    // ================= GEMM2: msgln = LN1(msg @ Wm) =================
    f32x4 acc[2][4] = {};
    for (int kt = 0; kt < 256; kt += 64) {
        #pragma unroll
        for (int i = 0; i < 4; ++i) {
            const int ch = i * 8 + w;
            async16(WmT + (long)(ch * 8 + lr) * 256 + kt + lc, &Bsm[ch * 512]);
        }
        __syncthreads();
        #pragma unroll
        for (int ks = 0; ks < 2; ++ks) {
            short8 a[2], bb[4];
            #pragma unroll
            for (int m = 0; m < 2; ++m)
                a[m] = *(const short8*)&QM[(wm*32 + m*16 + l15) * 264 + kt + ks*32 + lg*8];
            #pragma unroll
            for (int n = 0; n < 4; ++n)
                bb[n] = *(const short8*)&Bsm[(wn*64 + n*16 + l15)*64 + ks*32 + lg*8];
            #pragma unroll
            for (int m = 0; m < 2; ++m)
                #pragma unroll
                for (int n = 0; n < 4; ++n)
                    acc[m][n] = __builtin_amdgcn_mfma_f32_16x16x32_bf16(a[m], bb[n], acc[m][n], 0, 0, 0);
        }
        __syncthreads();
    }

    // LN1 epilogue
    #pragma unroll
    for (int m = 0; m < 2; ++m) {
        #pragma unroll
        for (int r = 0; r < 4; ++r) {
            float ls = 0.f, lq = 0.f;
            #pragma unroll
            for (int n = 0; n < 4; ++n) {
                const float v = acc[m][n][r];
                ls += v; lq += v * v;
            }
            #pragma unroll
            for (int o = 1; o < 16; o <<= 1) {
                ls += __shfl_xor(ls, o);
                lq += __shfl_xor(lq, o);
            }
            if (l15 == 0) {
                const int row = wm * 32 + m * 16 + lg * 4 + r;
                lnS[wn][row] = ls;
                lnQ[wn][row] = lq;
            }
        }
    }
    __syncthreads();

    float gv[4], bv[4];
    #pragma unroll
    for (int n = 0; n < 4; ++n) {
        const int col = wn * 64 + n * 16 + l15;
        gv[n] = g[col]; bv[n] = b[col];
    }
    #pragma unroll
    for (int m = 0; m < 2; ++m) {
        #pragma unroll
        for (int r = 0; r < 4; ++r) {
            const int row = wm * 32 + m * 16 + lg * 4 + r;
            const float S  = lnS[0][row] + lnS[1][row] + lnS[2][row] + lnS[3][row];
            const float Qq = lnQ[0][row] + lnQ[1][row] + lnQ[2][row] + lnQ[3][row];
            const float mean = S * (1.f / 256.f);
            const float var  = Qq * (1.f / 256.f) - mean * mean;
            const float rstd = rsqrtf(var + EPS_LN);
            const long grow = row0 + row;
            #pragma unroll
            for (int n = 0; n < 4; ++n) {
                const int col = wn * 64 + n * 16 + l15;
                const float y = (acc[m][n][r] - mean) * rstd * gv[n] + bv[n];
                msgln[grow * 256 + col] = __float2bfloat16(y);
            }
        }
    }
}

// ---------------------------------------------------------------------------
// Partial KV / Ksum. Grid (128 s-chunks, 4 batches), 64 rows per block.
// ---------------------------------------------------------------------------
__global__ __launch_bounds__(256)
void k_kv2(const bf16* __restrict__ Kb, const bf16* __restrict__ Vb,
           bf16* __restrict__ partKV, float* __restrict__ partKs)
{
    __shared__ __attribute__((aligned(16))) bf16 Kls[16 * 256];
    __shared__ __attribute__((aligned(16))) bf16 Vls[16 * 256];
    const int c = blockIdx.x;
    const int n = blockIdx.y;
    const int t = threadIdx.x;
    const int w = t >> 6, lane = t & 63;
    const int h = t >> 5, tt = t & 31, dg = tt >> 2, vg = tt & 3;
    float acc[4][8] = {};
    float ksacc[4] = {};
    const long base = ((long)n * 8192 + (long)c * 64) * 256;

    for (int s0 = 0; s0 < 64; s0 += 16) {
        #pragma unroll
        for (int p = 0; p < 2; ++p) {
            const int ch = p * 4 + w;
            async16(Kb + base + s0 * 256 + ch * 512 + lane * 8, &Kls[ch * 512]);
            async16(Vb + base + s0 * 256 + ch * 512 + lane * 8, &Vls[ch * 512]);
        }
        __syncthreads();
        #pragma unroll
        for (int i = 0; i < 16; ++i) {
            const bf16x4 kk = *(const bf16x4*)&Kls[i * 256 + h * 32 + dg * 4];
            const short8 vv = *(const short8*)&Vls[i * 256 + h * 32 + vg * 8];
            float kf[4], vf[8];
            #pragma unroll
            for (int j = 0; j < 4; ++j) { kf[j] = b2f(kk[j]); ksacc[j] += kf[j]; }
            #pragma unroll
            for (int u = 0; u < 8; ++u) vf[u] = b2f(vv[u]);
            #pragma unroll
            for (int j = 0; j < 4; ++j)
                #pragma unroll
                for (int u = 0; u < 8; ++u) acc[j][u] += kf[j] * vf[u];
        }
        __syncthreads();
    }

    const long pb = (long)(c * 4 + n) * 8192 + h * 1024;
    #pragma unroll
    for (int j = 0; j < 4; ++j) {
        short8 o;
        #pragma unroll
        for (int u = 0; u < 8; ++u) o[u] = f2b(acc[j][u]);
        *(short8*)&partKV[pb + (dg * 4 + j) * 32 + vg * 8] = o;
    }
    if (vg == 0) {
        f32x4 o4;
        #pragma unroll
        for (int j = 0; j < 4; ++j) o4[j] = ksacc[j];
        *(f32x4*)&partKs[(c * 4 + n) * 256 + h * 32 + dg * 4] = o4;
    }
}

// ---------------------------------------------------------------------------
// KV reduce stage 1: 128 -> 8 partials.
// ---------------------------------------------------------------------------
__global__ __launch_bounds__(256)
void k_kvred1(const bf16* __restrict__ partKV, const float* __restrict__ partKs,
              bf16* __restrict__ part2, float* __restrict__ part2Ks)
{
    const int bid = blockIdx.x;
    const int c8 = bid & 7, h = (bid >> 3) & 7, n = bid >> 6;
    const int t = threadIdx.x;
    const int d = t >> 3, vg = t & 7;
    float s[4] = {};
    #pragma unroll
    for (int i = 0; i < 16; ++i) {
        const int c = c8 * 16 + i;
        const bf16x4 p = *(const bf16x4*)&partKV[(long)(c * 4 + n) * 8192 + h * 1024 + d * 32 + vg * 4];
        #pragma unroll
        for (int j = 0; j < 4; ++j) s[j] += b2f(p[j]);
    }
    bf16x4 o;
    #pragma unroll
    for (int j = 0; j < 4; ++j) o[j] = f2b(s[j]);
    *(bf16x4*)&part2[(long)(c8 * 4 + n) * 8192 + h * 1024 + d * 32 + vg * 4] = o;
    if (vg == 0) {
        float ks = 0.f;
        #pragma unroll
        for (int i = 0; i < 16; ++i) {
            const int c = c8 * 16 + i;
            ks += partKs[(c * 4 + n) * 256 + h * 32 + d];
        }
        part2Ks[(c8 * 4 + n) * 256 + h * 32 + d] = ks;
    }
}

// ---------------------------------------------------------------------------
// KV reduce stage 2: 8 partials -> KVaug bf16 [n][h][32][48] (col 32 = Ksum)
// ---------------------------------------------------------------------------
__global__ __launch_bounds__(256)
void k_kvred2(const bf16* __restrict__ part2, const float* __restrict__ part2Ks,
              bf16* __restrict__ KVb)
{
    const int b = blockIdx.x;
    const int n = b >> 3, h = b & 7;
    const int t = threadIdx.x;
    const int d = t >> 3, vg = t & 7;
    float s[4] = {};
    #pragma unroll
    for (int c8 = 0; c8 < 8; ++c8) {
        const bf16x4 p = *(const bf16x4*)&part2[(long)(c8 * 4 + n) * 8192 + h * 1024 + d * 32 + vg * 4];
        #pragma unroll
        for (int j = 0; j < 4; ++j) s[j] += b2f(p[j]);
    }
    bf16* dst = KVb + ((long)n * 8 + h) * 1536 + d * 48;
    bf16x4 o;
    #pragma unroll
    for (int j = 0; j < 4; ++j) o[j] = f2b(s[j]);
    *(bf16x4*)&dst[vg * 4] = o;
    if (vg == 0) {
        float ks = 0.f;
        #pragma unroll
        for (int c8 = 0; c8 < 8; ++c8) ks += part2Ks[(c8 * 4 + n) * 256 + h * 32 + d];
        short8 z0 = {};
        z0[0] = f2b(ks);
        *(short8*)&dst[32] = z0;
        short8 zz = {};
        *(short8*)&dst[40] = zz;
    }
}

// ---------------------------------------------------------------------------
extern "C" void kernel_launch(void* const* d_in, const int* in_sizes, int n_in,
                              void* d_out, int out_size, void* d_ws, size_t ws_size,
                              hipStream_t stream)
{
    const float* x      = (const float*)d_in[0];
    const float* source = (const float*)d_in[1];
    const float* Wq     = (const float*)d_in[2];
    const float* Wk     = (const float*)d_in[3];
    const float* Wv     = (const float*)d_in[4];
    const float* Wm     = (const float*)d_in[5];
    const float* W1     = (const float*)d_in[6];
    const float* W2     = (const float*)d_in[7];
    const float* g1     = (const float*)d_in[8];
    const float* b1     = (const float*)d_in[9];
    const float* g2     = (const float*)d_in[10];
    const float* b2     = (const float*)d_in[11];
    float* out = (float*)d_out;

    const size_t U = 32768ull * 256ull;
    char* w = (char*)d_ws;

    // slots (16 MB each); lifetimes:
    bf16* x_bf  = (bf16*)(w + 0 * U * 2);   // alive through W1 gemm
    bf16* s_bf  = (bf16*)(w + 1 * U * 2);   // dead after KV gemm
    bf16* msgln = (bf16*)(w + 2 * U * 2);   // qaml out, alive through W1
    bf16* K_bf  = (bf16*)(w + 3 * U * 2);   // dead after k_kv2
    bf16* V_bf  = (bf16*)(w + 4 * U * 2);   // dead after k_kv2
    bf16* t_bf  = (bf16*)(w + 3 * U * 2);   // slots 3-4 ([32768,512]) after kv2

    char* wx = w + 7 * U * 2;
    bf16* WqT = (bf16*)wx; wx += 65536 * 2;
    bf16* WkT = (bf16*)wx; wx += 65536 * 2;   // contiguous with WvT -> [512][256]
    bf16* WvT = (bf16*)wx; wx += 65536 * 2;
    bf16* WmT = (bf16*)wx; wx += 65536 * 2;
    bf16* W1T = (bf16*)wx; wx += 262144 * 2;
    bf16* W2T = (bf16*)wx; wx += 131072 * 2;
    bf16* partKV = (bf16*)wx; wx += 4194304 * 2;   // 128 x 4 x 8192
    float* partKs = (float*)wx; wx += 131072 * 4;  // 128 x 4 x 256
    bf16* part2  = (bf16*)wx; wx += 262144 * 2;    // 8 x 4 x 8192
    float* part2Ks = (float*)wx; wx += 8192 * 4;   // 8 x 4 x 256
    bf16* KVb    = (bf16*)wx; wx += 49152 * 2;     // [n][h][32][48]

    const dim3 blk(256);

    // 1) prep: converts + all weight transposes (one launch)
    k_prep<<<8352, blk, 0, stream>>>(x, source, x_bf, s_bf,
                                     Wq, Wk, Wv, Wm, W1, W2,
                                     WqT, WkT, WvT, WmT, W1T, W2T);

    // 2) fused K+V projection (XCD-swizzled)
    k_gemmKV<<<dim3(256, 4), blk, 0, stream>>>(s_bf, WkT, K_bf, V_bf, 1.f / 8192.f);

    // 3) KV + Ksum -> KVaug (2-stage deterministic reduce)
    k_kv2<<<dim3(128, 4), blk, 0, stream>>>(K_bf, V_bf, partKV, partKs);
    k_kvred1<<<256, blk, 0, stream>>>(partKV, partKs, part2, part2Ks);
    k_kvred2<<<32, blk, 0, stream>>>(part2, part2Ks, KVb);

    // 4) MEGA: Q-proj + attn + merge + LN1 -> msgln
    k_qaml<<<512, dim3(512), 0, stream>>>(x_bf, WqT, WmT, KVb, g1, b1, msgln);

    // 5) MLP: t = relu([x_bf|msgln]@W1) (XCD-swizzled); out = x + LN2(t@W2)
    k_gemmW1<<<dim3(256, 4), blk, 0, stream>>>(x_bf, msgln, W1T, t_bf);
    k_gemm_ln2<<<512, dim3(512), 0, stream>>>(t_bf, W2T, g2, b2, x, out);
}

// Round 9
// 138.412 us; speedup vs baseline: 1.9531x; 1.0809x over previous
//
#include <hip/hip_runtime.h>
#include <hip/hip_bf16.h>
#include <stdint.h>

typedef __hip_bfloat16 bf16;
typedef __attribute__((ext_vector_type(8))) short short8;
typedef __attribute__((ext_vector_type(4))) short bf16x4;
typedef __attribute__((ext_vector_type(4))) float f32x4;

#define EPS_ATTN 1e-6f
#define EPS_LN   1e-5f

__device__ __forceinline__ float b2f(short s) {
    return __builtin_bit_cast(float, (unsigned)((unsigned short)s) << 16);
}
__device__ __forceinline__ short f2b(float f) {
    return __builtin_bit_cast(short, __float2bfloat16(f));
}

// ---------------------------------------------------------------------------
// async global->LDS, 16B per lane. LDS dest = wave-uniform base + lane*16.
// ---------------------------------------------------------------------------
__device__ __forceinline__ void async16(const void* g, void* l) {
    __builtin_amdgcn_global_load_lds(
        (const __attribute__((address_space(1))) void*)g,
        (__attribute__((address_space(3))) void*)l,
        16, 0, 0);
}

// ---------------------------------------------------------------------------
// Prep: fp32->bf16 converts (x, source) + all 6 weight transposes, ONE launch.
// blocks 0-4095 cvt x | 4096-8191 cvt source | 8192-8351 transposes
// ---------------------------------------------------------------------------
__global__ __launch_bounds__(256)
void k_prep(const float* __restrict__ x, const float* __restrict__ src,
            bf16* __restrict__ x_bf, bf16* __restrict__ s_bf,
            const float* __restrict__ Wq, const float* __restrict__ Wk,
            const float* __restrict__ Wv, const float* __restrict__ Wm,
            const float* __restrict__ W1, const float* __restrict__ W2,
            bf16* __restrict__ WqT, bf16* __restrict__ WkT,
            bf16* __restrict__ WvT, bf16* __restrict__ WmT,
            bf16* __restrict__ W1T, bf16* __restrict__ W2T)
{
    __shared__ float tile[64][65];
    const int blk = blockIdx.x;
    if (blk < 8192) {
        const float* in = (blk < 4096) ? x : src;
        bf16* out       = (blk < 4096) ? x_bf : s_bf;
        const long id = (long)(blk & 4095) * 256 + threadIdx.x;
        const float4 a = ((const float4*)in)[id * 2];
        const float4 b = ((const float4*)in)[id * 2 + 1];
        short8 o;
        o[0] = f2b(a.x); o[1] = f2b(a.y); o[2] = f2b(a.z); o[3] = f2b(a.w);
        o[4] = f2b(b.x); o[5] = f2b(b.y); o[6] = f2b(b.z); o[7] = f2b(b.w);
        ((short8*)out)[id] = o;
        return;
    }
    const int b = blk - 8192;
    const float* W; bf16* WT; int K, N, local;
    if      (b < 16)  { W = Wq; WT = WqT; K = 256; N = 256; local = b; }
    else if (b < 32)  { W = Wk; WT = WkT; K = 256; N = 256; local = b - 16; }
    else if (b < 48)  { W = Wv; WT = WvT; K = 256; N = 256; local = b - 32; }
    else if (b < 64)  { W = Wm; WT = WmT; K = 256; N = 256; local = b - 48; }
    else if (b < 128) { W = W1; WT = W1T; K = 512; N = 512; local = b - 64; }
    else              { W = W2; WT = W2T; K = 512; N = 256; local = b - 128; }
    const int tk = K / 64;
    const int k0 = (local % tk) * 64, n0 = (local / tk) * 64;
    const int ty = threadIdx.x >> 4, tx = threadIdx.x & 15;
    #pragma unroll
    for (int i = 0; i < 4; ++i) {
        const int k = ty + i * 16;
        const float4 v = *(const float4*)&W[(long)(k0 + k) * N + n0 + tx * 4];
        tile[k][tx * 4 + 0] = v.x; tile[k][tx * 4 + 1] = v.y;
        tile[k][tx * 4 + 2] = v.z; tile[k][tx * 4 + 3] = v.w;
    }
    __syncthreads();
    #pragma unroll
    for (int i = 0; i < 4; ++i) {
        const int n = ty + i * 16;
        bf16x4 o;
        #pragma unroll
        for (int j = 0; j < 4; ++j) o[j] = f2b(tile[tx * 4 + j][n]);
        *(bf16x4*)&WT[(long)(n0 + n) * K + k0 + tx * 4] = o;
    }
}

// ---------------------------------------------------------------------------
// FUSED K/V projection + feature-map + partial-KV/Ksum. No K_bf/V_bf round
// trip. Grid (256 row-chunks, 2 head-halves), 512 thr, 8 waves (2M x 4N).
// Block: rows cid*128..+128, head-half hh (heads hh*4..hh*4+3 = 128 K cols +
// 128 V cols). Phase1: GEMM vs [WkT;WvT] panels. Phase2: fmap -> K/V tiles in
// LDS (aliases dead staging). Phase3: partKV[cid][h][d][v] over 128 rows.
// ---------------------------------------------------------------------------
__global__ __launch_bounds__(512)
void k_kvproj(const bf16* __restrict__ A, const bf16* __restrict__ BT,
              bf16* __restrict__ partKV, float* __restrict__ partKs,
              float escale)
{
    __shared__ __attribute__((aligned(16))) bf16 S[32768];   // 64 KB union
    bf16* Asm = S;            // [0,8192)   phase 1
    bf16* Bsm = S + 8192;     // [8192,24576) phase 1
    bf16* KT  = S;            // [0,16384)  phase 2/3 (128x128)
    bf16* VT  = S + 16384;    // [16384,32768)

    const int t = threadIdx.x, w = t >> 6, lane = t & 63;
    const int wm = w >> 2, wn = w & 3;
    const int flat = blockIdx.y * gridDim.x + blockIdx.x;   // 0..511
    const int swz  = (flat & 7) * 64 + (flat >> 3);         // bijective, XCD
    const int cid  = swz >> 1;                              // 0..255
    const int hh   = swz & 1;                               // head half
    const long row0 = (long)cid * 128;
    const int lr = lane >> 3, lc = (lane & 7) * 8;
    const int lg = lane >> 4, l15 = lane & 15;

    f32x4 acc[4][4] = {};

    for (int kt = 0; kt < 256; kt += 64) {
        #pragma unroll
        for (int i = 0; i < 2; ++i) {                        // A: 16 groups
            const int g = w * 2 + i;
            async16(A + (row0 + g * 8 + lr) * 256 + kt + lc, &Asm[g * 512]);
        }
        #pragma unroll
        for (int i = 0; i < 4; ++i) {                        // B: 32 groups
            const int g = w * 4 + i;
            const long brow = (g < 16)
                ? (long)(hh * 128 + g * 8 + lr)              // WkT panel
                : (long)(256 + hh * 128 + (g - 16) * 8 + lr);// WvT panel
            async16(BT + brow * 256 + kt + lc, &Bsm[g * 512]);
        }
        __syncthreads();
        #pragma unroll
        for (int ks = 0; ks < 2; ++ks) {
            short8 a[4], b[4];
            #pragma unroll
            for (int m = 0; m < 4; ++m)
                a[m] = *(const short8*)&Asm[(wm*64 + m*16 + l15)*64 + ks*32 + lg*8];
            #pragma unroll
            for (int n = 0; n < 4; ++n)
                b[n] = *(const short8*)&Bsm[(wn*64 + n*16 + l15)*64 + ks*32 + lg*8];
            #pragma unroll
            for (int m = 0; m < 4; ++m)
                #pragma unroll
                for (int n = 0; n < 4; ++n)
                    acc[m][n] = __builtin_amdgcn_mfma_f32_16x16x32_bf16(a[m], b[n], acc[m][n], 0, 0, 0);
        }
        __syncthreads();   // staging LDS dead after this (last iter)
    }

    // ---- phase 2: feature-map + write K/V tiles (aliases staging) ----
    const bool isK = wn < 2;
    bf16* tile = isK ? KT : VT;
    #pragma unroll
    for (int m = 0; m < 4; ++m) {
        #pragma unroll
        for (int n = 0; n < 4; ++n) {
            #pragma unroll
            for (int r = 0; r < 4; ++r) {
                const int row = wm * 64 + m * 16 + lg * 4 + r;
                const int col = (wn & 1) * 64 + n * 16 + l15;
                float v = acc[m][n][r];
                if (isK) v = v > 0.f ? v + 1.f : __expf(v);
                else     v *= escale;
                tile[row * 128 + col] = __float2bfloat16(v);
            }
        }
    }
    __syncthreads();

    // ---- phase 3: partKV[h][d][v] = sum over 128 rows; Ksum too ----
    const int h_l = t >> 7;            // 0..3 (local head)
    const int d   = (t & 127) >> 2;    // 0..31
    const int vg  = t & 3;             // 8 v's each
    float a2[8] = {};
    float ks = 0.f;
    #pragma unroll 4
    for (int row = 0; row < 128; ++row) {
        const float kd = __bfloat162float(KT[row * 128 + h_l * 32 + d]);
        ks += kd;
        const short8 vv = *(const short8*)&VT[row * 128 + h_l * 32 + vg * 8];
        #pragma unroll
        for (int u = 0; u < 8; ++u) a2[u] += kd * b2f(vv[u]);
    }
    short8 o;
    #pragma unroll
    for (int u = 0; u < 8; ++u) o[u] = f2b(a2[u]);
    *(short8*)&partKV[(long)cid * 8192 + (hh * 4 + h_l) * 1024 + d * 32 + vg * 8] = o;
    if (vg == 0) partKs[cid * 256 + (hh * 4 + h_l) * 32 + d] = ks;
}

// ---------------------------------------------------------------------------
// KV reduce stage 1: 64 chunks/batch -> 8 partials. Grid 256 = (n<<6)|(h<<3)|c8
// partKV layout: [cid][h][d][v], cid = n*64 + i.
// ---------------------------------------------------------------------------
__global__ __launch_bounds__(256)
void k_kvred1(const bf16* __restrict__ partKV, const float* __restrict__ partKs,
              bf16* __restrict__ part2, float* __restrict__ part2Ks)
{
    const int bid = blockIdx.x;
    const int c8 = bid & 7, h = (bid >> 3) & 7, n = bid >> 6;
    const int t = threadIdx.x;
    const int d = t >> 3, vg = t & 7;
    float s[4] = {};
    #pragma unroll
    for (int j = 0; j < 8; ++j) {
        const int cid = n * 64 + c8 * 8 + j;
        const bf16x4 p = *(const bf16x4*)&partKV[(long)cid * 8192 + h * 1024 + d * 32 + vg * 4];
        #pragma unroll
        for (int jj = 0; jj < 4; ++jj) s[jj] += b2f(p[jj]);
    }
    bf16x4 o;
    #pragma unroll
    for (int jj = 0; jj < 4; ++jj) o[jj] = f2b(s[jj]);
    *(bf16x4*)&part2[(long)(c8 * 4 + n) * 8192 + h * 1024 + d * 32 + vg * 4] = o;
    if (vg == 0) {
        float ks = 0.f;
        #pragma unroll
        for (int j = 0; j < 8; ++j) {
            const int cid = n * 64 + c8 * 8 + j;
            ks += partKs[cid * 256 + h * 32 + d];
        }
        part2Ks[(c8 * 4 + n) * 256 + h * 32 + d] = ks;
    }
}

// ---------------------------------------------------------------------------
// KV reduce stage 2: 8 partials -> KVaug bf16 [n][h][32][48] (col 32 = Ksum)
// ---------------------------------------------------------------------------
__global__ __launch_bounds__(256)
void k_kvred2(const bf16* __restrict__ part2, const float* __restrict__ part2Ks,
              bf16* __restrict__ KVb)
{
    const int b = blockIdx.x;
    const int n = b >> 3, h = b & 7;
    const int t = threadIdx.x;
    const int d = t >> 3, vg = t & 7;
    float s[4] = {};
    #pragma unroll
    for (int c8 = 0; c8 < 8; ++c8) {
        const bf16x4 p = *(const bf16x4*)&part2[(long)(c8 * 4 + n) * 8192 + h * 1024 + d * 32 + vg * 4];
        #pragma unroll
        for (int j = 0; j < 4; ++j) s[j] += b2f(p[j]);
    }
    bf16* dst = KVb + ((long)n * 8 + h) * 1536 + d * 48;
    bf16x4 o;
    #pragma unroll
    for (int j = 0; j < 4; ++j) o[j] = f2b(s[j]);
    *(bf16x4*)&dst[vg * 4] = o;
    if (vg == 0) {
        float ks = 0.f;
        #pragma unroll
        for (int c8 = 0; c8 < 8; ++c8) ks += part2Ks[(c8 * 4 + n) * 256 + h * 32 + d];
        short8 z0 = {};
        z0[0] = f2b(ks);
        *(short8*)&dst[32] = z0;
        short8 zz = {};
        *(short8*)&dst[40] = zz;
    }
}

// ---------------------------------------------------------------------------
// MEGA: Q-proj + feature-map + attention + merge-GEMM + LN1 in one kernel.
// Block = 64 rows, 512 thr, 8 waves. msgln = LN1( attn(fmap(x@Wq)) @ Wm ).
// Fragment row/col index is l15; lr is ONLY for staging (R7 bug).
// ---------------------------------------------------------------------------
__global__ __launch_bounds__(512)
void k_qaml(const bf16* __restrict__ xb, const bf16* __restrict__ WqT,
            const bf16* __restrict__ WmT, const bf16* __restrict__ KVb,
            const float* __restrict__ g, const float* __restrict__ b,
            bf16* __restrict__ msgln)
{
    __shared__ __attribute__((aligned(16))) bf16 Asm[64 * 64];
    __shared__ __attribute__((aligned(16))) bf16 Bsm[256 * 64];
    __shared__ __attribute__((aligned(16))) bf16 QM[64 * 264];
    __shared__ float lnS[4][64];
    __shared__ float lnQ[4][64];
    const int t = threadIdx.x, w = t >> 6, lane = t & 63;
    const int wm = w >> 2, wn = w & 3;
    const long row0 = (long)blockIdx.x * 64;
    const int n_b = (int)(row0 >> 13);             // batch index
    const int lr = lane >> 3, lc = (lane & 7) * 8;
    const int lg = lane >> 4, l15 = lane & 15;

    // ================= GEMM1: Q = fmap(x @ Wq) =================
    {
        f32x4 acc[2][4] = {};
        for (int kt = 0; kt < 256; kt += 64) {
            async16(xb + (row0 + w * 8 + lr) * 256 + kt + lc, &Asm[w * 512]);
            #pragma unroll
            for (int i = 0; i < 4; ++i) {
                const int ch = i * 8 + w;
                async16(WqT + (long)(ch * 8 + lr) * 256 + kt + lc, &Bsm[ch * 512]);
            }
            __syncthreads();
            #pragma unroll
            for (int ks = 0; ks < 2; ++ks) {
                short8 a[2], bb[4];
                #pragma unroll
                for (int m = 0; m < 2; ++m)
                    a[m] = *(const short8*)&Asm[(wm*32 + m*16 + l15)*64 + ks*32 + lg*8];
                #pragma unroll
                for (int n = 0; n < 4; ++n)
                    bb[n] = *(const short8*)&Bsm[(wn*64 + n*16 + l15)*64 + ks*32 + lg*8];
                #pragma unroll
                for (int m = 0; m < 2; ++m)
                    #pragma unroll
                    for (int n = 0; n < 4; ++n)
                        acc[m][n] = __builtin_amdgcn_mfma_f32_16x16x32_bf16(a[m], bb[n], acc[m][n], 0, 0, 0);
            }
            __syncthreads();
        }
        #pragma unroll
        for (int m = 0; m < 2; ++m) {
            #pragma unroll
            for (int n = 0; n < 4; ++n) {
                #pragma unroll
                for (int r = 0; r < 4; ++r) {
                    const int row = wm * 32 + m * 16 + lg * 4 + r;
                    const int col = wn * 64 + n * 16 + l15;
                    float v = acc[m][n][r];
                    v = v > 0.f ? v + 1.f : __expf(v);
                    QM[row * 264 + col] = __float2bfloat16(v);
                }
            }
        }
    }
    __syncthreads();

    // ================= attention: wave w = head w ================
    {
        const bf16* kvh = KVb + (long)n_b * 12288 + w * 1536;
        short8 b0, b1, bz;
        #pragma unroll
        for (int j = 0; j < 8; ++j) {
            const int drow = (lg * 8 + j) * 48;
            b0[j] = __builtin_bit_cast(short, kvh[drow + l15]);
            b1[j] = __builtin_bit_cast(short, kvh[drow + 16 + l15]);
            bz[j] = __builtin_bit_cast(short, kvh[drow + 32 + l15]);
        }
        f32x4 ra0[4], ra1[4];
        #pragma unroll
        for (int m2 = 0; m2 < 4; ++m2) {
            const short8 a = *(const short8*)&QM[(m2 * 16 + l15) * 264 + w * 32 + lg * 8];
            f32x4 a0 = {}, a1 = {}, az = {};
            a0 = __builtin_amdgcn_mfma_f32_16x16x32_bf16(a, b0, a0, 0, 0, 0);
            a1 = __builtin_amdgcn_mfma_f32_16x16x32_bf16(a, b1, a1, 0, 0, 0);
            az = __builtin_amdgcn_mfma_f32_16x16x32_bf16(a, bz, az, 0, 0, 0);
            #pragma unroll
            for (int r = 0; r < 4; ++r) {
                const float z   = __shfl(az[r], lane & 48);
                const float inv = 8192.f / (z + EPS_ATTN);
                ra0[m2][r] = a0[r] * inv;
                ra1[m2][r] = a1[r] * inv;
            }
        }
        __syncthreads();   // all QM (Q) reads done, safe to overwrite
        #pragma unroll
        for (int m2 = 0; m2 < 4; ++m2) {
            #pragma unroll
            for (int r = 0; r < 4; ++r) {
                const int row = m2 * 16 + lg * 4 + r;
                QM[row * 264 + w * 32 + l15]      = __float2bfloat16(ra0[m2][r]);
                QM[row * 264 + w * 32 + 16 + l15] = __float2bfloat16(ra1[m2][r]);
            }
        }
    }
    __syncthreads();

    // ================= GEMM2: msgln = LN1(msg @ Wm) =================
    f32x4 acc[2][4] = {};
    for (int kt = 0; kt < 256; kt += 64) {
        #pragma unroll
        for (int i = 0; i < 4; ++i) {
            const int ch = i * 8 + w;
            async16(WmT + (long)(ch * 8 + lr) * 256 + kt + lc, &Bsm[ch * 512]);
        }
        __syncthreads();
        #pragma unroll
        for (int ks = 0; ks < 2; ++ks) {
            short8 a[2], bb[4];
            #pragma unroll
            for (int m = 0; m < 2; ++m)
                a[m] = *(const short8*)&QM[(wm*32 + m*16 + l15) * 264 + kt + ks*32 + lg*8];
            #pragma unroll
            for (int n = 0; n < 4; ++n)
                bb[n] = *(const short8*)&Bsm[(wn*64 + n*16 + l15)*64 + ks*32 + lg*8];
            #pragma unroll
            for (int m = 0; m < 2; ++m)
                #pragma unroll
                for (int n = 0; n < 4; ++n)
                    acc[m][n] = __builtin_amdgcn_mfma_f32_16x16x32_bf16(a[m], bb[n], acc[m][n], 0, 0, 0);
        }
        __syncthreads();
    }

    // LN1 epilogue
    #pragma unroll
    for (int m = 0; m < 2; ++m) {
        #pragma unroll
        for (int r = 0; r < 4; ++r) {
            float ls = 0.f, lq = 0.f;
            #pragma unroll
            for (int n = 0; n < 4; ++n) {
                const float v = acc[m][n][r];
                ls += v; lq += v * v;
            }
            #pragma unroll
            for (int o = 1; o < 16; o <<= 1) {
                ls += __shfl_xor(ls, o);
                lq += __shfl_xor(lq, o);
            }
            if (l15 == 0) {
                const int row = wm * 32 + m * 16 + lg * 4 + r;
                lnS[wn][row] = ls;
                lnQ[wn][row] = lq;
            }
        }
    }
    __syncthreads();

    float gv[4], bv[4];
    #pragma unroll
    for (int n = 0; n < 4; ++n) {
        const int col = wn * 64 + n * 16 + l15;
        gv[n] = g[col]; bv[n] = b[col];
    }
    #pragma unroll
    for (int m = 0; m < 2; ++m) {
        #pragma unroll
        for (int r = 0; r < 4; ++r) {
            const int row = wm * 32 + m * 16 + lg * 4 + r;
            const float S  = lnS[0][row] + lnS[1][row] + lnS[2][row] + lnS[3][row];
            const float Qq = lnQ[0][row] + lnQ[1][row] + lnQ[2][row] + lnQ[3][row];
            const float mean = S * (1.f / 256.f);
            const float var  = Qq * (1.f / 256.f) - mean * mean;
            const float rstd = rsqrtf(var + EPS_LN);
            const long grow = row0 + row;
            #pragma unroll
            for (int n = 0; n < 4; ++n) {
                const int col = wn * 64 + n * 16 + l15;
                const float y = (acc[m][n][r] - mean) * rstd * gv[n] + bv[n];
                msgln[grow * 256 + col] = __float2bfloat16(y);
            }
        }
    }
}

// ---------------------------------------------------------------------------
// W1 GEMM, split-K A (virtual hcat = [A0|A1]), XCD-swizzled.
// ---------------------------------------------------------------------------
__global__ __launch_bounds__(256)
void k_gemmW1(const bf16* __restrict__ A0, const bf16* __restrict__ A1,
              const bf16* __restrict__ BT, bf16* __restrict__ C)
{
    __shared__ __attribute__((aligned(16))) bf16 Asm[128 * 64];
    __shared__ __attribute__((aligned(16))) bf16 Bsm[128 * 64];
    const int tid  = threadIdx.x;
    const int wave = tid >> 6, lane = tid & 63;
    const int wm = wave >> 1, wn = wave & 1;
    const int flat = blockIdx.y * gridDim.x + blockIdx.x;          // 0..1023
    const int swz  = (flat & 7) * 128 + (flat >> 3);
    const long row0 = (long)(swz >> 2) * 128;
    const long col0 = (long)(swz & 3) * 128;

    f32x4 acc[4][4] = {};
    const int lr = lane >> 3;
    const int lc = (lane & 7) * 8;

    for (int kt = 0; kt < 512; kt += 64) {
        const bf16* Asrc = (kt < 256) ? A0 : A1;
        const int kk = kt & 255;
        #pragma unroll
        for (int i = 0; i < 4; ++i) {
            const int grp = wave * 4 + i;
            const long r  = grp * 8 + lr;
            async16(Asrc + (row0 + r) * 256 + kk + lc, &Asm[grp * 512]);
            async16(BT   + (col0 + r) * 512 + kt + lc, &Bsm[grp * 512]);
        }
        __syncthreads();
        #pragma unroll
        for (int ks = 0; ks < 2; ++ks) {
            short8 a[4], b[4];
            #pragma unroll
            for (int m = 0; m < 4; ++m)
                a[m] = *(const short8*)&Asm[(wm*64 + m*16 + (lane & 15))*64 + ks*32 + (lane>>4)*8];
            #pragma unroll
            for (int n = 0; n < 4; ++n)
                b[n] = *(const short8*)&Bsm[(wn*64 + n*16 + (lane & 15))*64 + ks*32 + (lane>>4)*8];
            #pragma unroll
            for (int m = 0; m < 4; ++m)
                #pragma unroll
                for (int n = 0; n < 4; ++n)
                    acc[m][n] = __builtin_amdgcn_mfma_f32_16x16x32_bf16(a[m], b[n], acc[m][n], 0, 0, 0);
        }
        __syncthreads();
    }

    #pragma unroll
    for (int m = 0; m < 4; ++m) {
        #pragma unroll
        for (int n = 0; n < 4; ++n) {
            #pragma unroll
            for (int r = 0; r < 4; ++r) {
                const long row = row0 + wm*64 + m*16 + (lane >> 4)*4 + r;
                const long col = col0 + wn*64 + n*16 + (lane & 15);
                const float v = acc[m][n][r];
                C[row * 512 + col] = __float2bfloat16(v > 0.f ? v : 0.f);
            }
        }
    }
}

// ---------------------------------------------------------------------------
// Fused GEMM(K=512) + LN2 + residual: out = fp32 x + LN(A@B). 64x256 tile,
// 8 waves, 512 threads, grid M/64.
// ---------------------------------------------------------------------------
__global__ __launch_bounds__(512)
void k_gemm_ln2(const bf16* __restrict__ A, const bf16* __restrict__ BT,
                const float* __restrict__ g, const float* __restrict__ b,
                const float* __restrict__ xres, float* __restrict__ out)
{
    __shared__ __attribute__((aligned(16))) bf16 Asm[64 * 64];
    __shared__ __attribute__((aligned(16))) bf16 Bsm[256 * 64];
    __shared__ float lnS[4][64];
    __shared__ float lnQ[4][64];
    const int t = threadIdx.x, w = t >> 6, lane = t & 63;
    const int wm = w >> 2, wn = w & 3;
    const long row0 = (long)blockIdx.x * 64;
    const int lr = lane >> 3, lc = (lane & 7) * 8;
    const int lg = lane >> 4, l15 = lane & 15;

    f32x4 acc[2][4] = {};

    for (int kt = 0; kt < 512; kt += 64) {
        async16(A + (row0 + w * 8 + lr) * 512 + kt + lc, &Asm[w * 512]);
        #pragma unroll
        for (int i = 0; i < 4; ++i) {
            const int ch = i * 8 + w;
            async16(BT + (long)(ch * 8 + lr) * 512 + kt + lc, &Bsm[ch * 512]);
        }
        __syncthreads();
        #pragma unroll
        for (int ks = 0; ks < 2; ++ks) {
            short8 a[2], bb[4];
            #pragma unroll
            for (int m = 0; m < 2; ++m)
                a[m] = *(const short8*)&Asm[(wm*32 + m*16 + l15)*64 + ks*32 + lg*8];
            #pragma unroll
            for (int n = 0; n < 4; ++n)
                bb[n] = *(const short8*)&Bsm[(wn*64 + n*16 + l15)*64 + ks*32 + lg*8];
            #pragma unroll
            for (int m = 0; m < 2; ++m)
                #pragma unroll
                for (int n = 0; n < 4; ++n)
                    acc[m][n] = __builtin_amdgcn_mfma_f32_16x16x32_bf16(a[m], bb[n], acc[m][n], 0, 0, 0);
        }
        __syncthreads();
    }

    #pragma unroll
    for (int m = 0; m < 2; ++m) {
        #pragma unroll
        for (int r = 0; r < 4; ++r) {
            float ls = 0.f, lq = 0.f;
            #pragma unroll
            for (int n = 0; n < 4; ++n) {
                const float v = acc[m][n][r];
                ls += v; lq += v * v;
            }
            #pragma unroll
            for (int o = 1; o < 16; o <<= 1) {
                ls += __shfl_xor(ls, o);
                lq += __shfl_xor(lq, o);
            }
            if (l15 == 0) {
                const int row = wm * 32 + m * 16 + lg * 4 + r;
                lnS[wn][row] = ls;
                lnQ[wn][row] = lq;
            }
        }
    }
    __syncthreads();

    float gv[4], bv[4];
    #pragma unroll
    for (int n = 0; n < 4; ++n) {
        const int col = wn * 64 + n * 16 + l15;
        gv[n] = g[col]; bv[n] = b[col];
    }
    #pragma unroll
    for (int m = 0; m < 2; ++m) {
        #pragma unroll
        for (int r = 0; r < 4; ++r) {
            const int row = wm * 32 + m * 16 + lg * 4 + r;
            const float S  = lnS[0][row] + lnS[1][row] + lnS[2][row] + lnS[3][row];
            const float Qq = lnQ[0][row] + lnQ[1][row] + lnQ[2][row] + lnQ[3][row];
            const float mean = S * (1.f / 256.f);
            const float var  = Qq * (1.f / 256.f) - mean * mean;
            const float rstd = rsqrtf(var + EPS_LN);
            const long grow = row0 + row;
            #pragma unroll
            for (int n = 0; n < 4; ++n) {
                const int col = wn * 64 + n * 16 + l15;
                const float y = (acc[m][n][r] - mean) * rstd * gv[n] + bv[n];
                out[grow * 256 + col] = xres[grow * 256 + col] + y;
            }
        }
    }
}

// ---------------------------------------------------------------------------
extern "C" void kernel_launch(void* const* d_in, const int* in_sizes, int n_in,
                              void* d_out, int out_size, void* d_ws, size_t ws_size,
                              hipStream_t stream)
{
    const float* x      = (const float*)d_in[0];
    const float* source = (const float*)d_in[1];
    const float* Wq     = (const float*)d_in[2];
    const float* Wk     = (const float*)d_in[3];
    const float* Wv     = (const float*)d_in[4];
    const float* Wm     = (const float*)d_in[5];
    const float* W1     = (const float*)d_in[6];
    const float* W2     = (const float*)d_in[7];
    const float* g1     = (const float*)d_in[8];
    const float* b1     = (const float*)d_in[9];
    const float* g2     = (const float*)d_in[10];
    const float* b2     = (const float*)d_in[11];
    float* out = (float*)d_out;

    const size_t U = 32768ull * 256ull;
    char* w = (char*)d_ws;

    // slots (16 MB each); lifetimes:
    bf16* x_bf  = (bf16*)(w + 0 * U * 2);   // alive through W1 gemm
    bf16* s_bf  = (bf16*)(w + 1 * U * 2);   // dead after k_kvproj
    bf16* msgln = (bf16*)(w + 2 * U * 2);   // qaml out, alive through W1
    bf16* t_bf  = (bf16*)(w + 3 * U * 2);   // slots 3-4 ([32768,512])

    char* wx = w + 7 * U * 2;
    bf16* WqT = (bf16*)wx; wx += 65536 * 2;
    bf16* WkT = (bf16*)wx; wx += 65536 * 2;   // contiguous with WvT -> [512][256]
    bf16* WvT = (bf16*)wx; wx += 65536 * 2;
    bf16* WmT = (bf16*)wx; wx += 65536 * 2;
    bf16* W1T = (bf16*)wx; wx += 262144 * 2;
    bf16* W2T = (bf16*)wx; wx += 131072 * 2;
    bf16* partKV = (bf16*)wx; wx += 2097152 * 2;   // 256 cid x 8192
    float* partKs = (float*)wx; wx += 65536 * 4;   // 256 cid x 256
    bf16* part2  = (bf16*)wx; wx += 262144 * 2;    // 8 x 4 x 8192
    float* part2Ks = (float*)wx; wx += 8192 * 4;   // 8 x 4 x 256
    bf16* KVb    = (bf16*)wx; wx += 49152 * 2;     // [n][h][32][48]

    const dim3 blk(256);

    // 1) prep: converts + all weight transposes (one launch)
    k_prep<<<8352, blk, 0, stream>>>(x, source, x_bf, s_bf,
                                     Wq, Wk, Wv, Wm, W1, W2,
                                     WqT, WkT, WvT, WmT, W1T, W2T);

    // 2) FUSED K/V projection + partial KV/Ksum (no K_bf/V_bf round trip)
    k_kvproj<<<dim3(256, 2), dim3(512), 0, stream>>>(s_bf, WkT, partKV, partKs,
                                                     1.f / 8192.f);

    // 3) reduce partials -> KVaug
    k_kvred1<<<256, blk, 0, stream>>>(partKV, partKs, part2, part2Ks);
    k_kvred2<<<32, blk, 0, stream>>>(part2, part2Ks, KVb);

    // 4) MEGA: Q-proj + attn + merge + LN1 -> msgln
    k_qaml<<<512, dim3(512), 0, stream>>>(x_bf, WqT, WmT, KVb, g1, b1, msgln);

    // 5) MLP: t = relu([x_bf|msgln]@W1) (XCD-swizzled); out = x + LN2(t@W2)
    k_gemmW1<<<dim3(256, 4), blk, 0, stream>>>(x_bf, msgln, W1T, t_bf);
    k_gemm_ln2<<<512, dim3(512), 0, stream>>>(t_bf, W2T, g2, b2, x, out);
}